// Round 17
// baseline (208.539 us; speedup 1.0000x reference)
//
#include <hip/hip_runtime.h>
#include <hip/hip_bf16.h>

using u16 = unsigned short;
using u32 = unsigned int;

typedef short bf16x8 __attribute__((ext_vector_type(8)));
typedef float f32x4 __attribute__((ext_vector_type(4)));

#define AS1 __attribute__((address_space(1)))
#define AS3 __attribute__((address_space(3)))

__device__ __forceinline__ void gll16(const void* g, void* l) {
  __builtin_amdgcn_global_load_lds((const AS1 u32*)g, (AS3 u32*)l, 16, 0, 0);
}

__device__ __forceinline__ u16 f2bf(float x) {  // round-to-nearest-even bf16
  u32 u = __builtin_bit_cast(u32, x);
  u32 r = (u + 0x7fffu + ((u >> 16) & 1u)) >> 16;
  return (u16)r;
}
__device__ __forceinline__ u32 pk2(float lo, float hi) {
  return (u32)f2bf(lo) | ((u32)f2bf(hi) << 16);
}
__device__ __forceinline__ u16 f2bf_fast(float x) {  // hw cvt (validated r5/r6)
  __hip_bfloat16 h = __float2bfloat16(x);
  return __builtin_bit_cast(u16, h);
}

// ---------------- merged prep: x cast + 4 weight transposes + fused cos/sin table ----------------
__device__ __forceinline__ void trans64(const float* __restrict__ in, u16* __restrict__ out,
                                        int R, int Cc, int bx, int by, float (*tl)[65]) {
  int c0 = bx * 64, r0 = by * 64, tid = threadIdx.x;
#pragma unroll
  for (int i = 0; i < 16; i++) {
    int idx = i * 256 + tid; int tr = idx >> 6, tc = idx & 63;
    tl[tr][tc] = in[(size_t)(r0 + tr) * Cc + c0 + tc];
  }
  __syncthreads();
#pragma unroll
  for (int i = 0; i < 16; i++) {
    int idx = i * 256 + tid; int tr = idx >> 6, tc = idx & 63;
    out[(size_t)(c0 + tr) * R + r0 + tc] = f2bf(tl[tc][tr]);
  }
}

__global__ void k_prep(const float* __restrict__ x, u16* __restrict__ xb,
                       const float* __restrict__ wq, u16* __restrict__ wqt,
                       const float* __restrict__ wk, const float* __restrict__ wv,
                       u16* __restrict__ wkvt,
                       const float* __restrict__ wo, u16* __restrict__ wot,
                       const float* __restrict__ fc, const float* __restrict__ fs,
                       float2* __restrict__ fcs) {
  __shared__ float tl[64][65];
  int gid = blockIdx.x;
  if (gid < 4096) {
    int i = gid * 256 + threadIdx.x;
    const float4* p = (const float4*)(x + (size_t)i * 8);
    float4 a = p[0], b = p[1];
    uint4 o;
    o.x = pk2(a.x, a.y); o.y = pk2(a.z, a.w);
    o.z = pk2(b.x, b.y); o.w = pk2(b.z, b.w);
    *(uint4*)(xb + (size_t)i * 8) = o;
  } else if (gid < 5120) {
    int t = gid - 4096; trans64(wq, wqt, 2048, 2048, t & 31, t >> 5, tl);
  } else if (gid < 5376) {
    int t = gid - 5120; trans64(wk, wkvt, 2048, 512, t & 7, t >> 3, tl);
  } else if (gid < 5632) {
    int t = gid - 5376; trans64(wv, wkvt + 512 * 2048, 2048, 512, t & 7, t >> 3, tl);
  } else if (gid < 6656) {
    int t = gid - 5632; trans64(wo, wot, 2048, 2048, t & 31, t >> 5, tl);
  } else {
    int base = (gid - 6656) * 2048 + threadIdx.x * 8;
#pragma unroll
    for (int j = 0; j < 8; j++) {
      int idx = base + j;
      fcs[idx] = make_float2(fc[idx], fs[idx]);
    }
  }
}

// ---------------- O-projection GEMM (proven r15 path, MODE 0 only) ----------------
template <int MODE>
__global__ __launch_bounds__(256) void k_gemm(
    const u16* __restrict__ A, const u16* __restrict__ BT0, const u16* __restrict__ BT1,
    void* __restrict__ Cout, u16* __restrict__ Kout, u16* __restrict__ Vout, int K,
    const float* __restrict__ nwq, const float* __restrict__ nwk,
    const float2* __restrict__ fcs) {
  constexpr int NX = 16;
  constexpr int RBX = 8;
  __shared__ char lds[32768];
  char* As = lds; char* Bs = lds + 16384;
  int tid = threadIdx.x, w = tid >> 6, l = tid & 63, lg = l >> 4, ll = l & 15;
  int lid = blockIdx.y * NX + blockIdx.x;
  int xcd = lid & 7, r = lid >> 3;
  int colg = xcd & 1, rowg = xcd >> 1;
  int bxt = colg * RBX + r % RBX;
  int bm0 = (rowg * 8 + r / RBX) * 128;
  const u16* BT = BT0;
  int bn0 = bxt * 128;
  int wr = w >> 1, wc = w & 1;
  f32x4 acc[4][4] = {};
  for (int k0 = 0; k0 < K; k0 += 64) {
#pragma unroll
    for (int i = 0; i < 4; i++) {
      int base = i * 256 + (w << 6);
      int p = base + l;
      int rr = p >> 3, kc = (p & 7) ^ (rr & 7);
      gll16(A + (size_t)(bm0 + rr) * K + k0 + kc * 8, As + base * 16);
      gll16(BT + (size_t)(bn0 + rr) * K + k0 + kc * 8, Bs + base * 16);
    }
    asm volatile("s_waitcnt vmcnt(0)" ::: "memory");
    __syncthreads();
#pragma unroll
    for (int ks = 0; ks < 2; ks++) {
      bf16x8 af[4], bfr[4];
#pragma unroll
      for (int m = 0; m < 4; m++) {
        int row = 64 * wr + 16 * m + ll;
        af[m] = *(const bf16x8*)(As + row * 128 + (((lg + 4 * ks) ^ (row & 7)) << 4));
      }
#pragma unroll
      for (int n = 0; n < 4; n++) {
        int row = 64 * wc + 16 * n + ll;
        bfr[n] = *(const bf16x8*)(Bs + row * 128 + (((lg + 4 * ks) ^ (row & 7)) << 4));
      }
#pragma unroll
      for (int m = 0; m < 4; m++)
#pragma unroll
        for (int n = 0; n < 4; n++)
          acc[m][n] = __builtin_amdgcn_mfma_f32_16x16x32_bf16(af[m], bfr[n], acc[m][n], 0, 0, 0);
    }
    __syncthreads();
  }
  float* C = (float*)Cout;
#pragma unroll
  for (int m = 0; m < 4; m++)
#pragma unroll
    for (int n = 0; n < 4; n++) {
      int row = bm0 + 64 * wr + 16 * m + 4 * lg;
      int col = bn0 + 64 * wc + 16 * n + ll;
      float* cp = C + (size_t)row * 2048 + col;
#pragma unroll
      for (int r2 = 0; r2 < 4; r2++) cp[(size_t)r2 * 2048] = acc[m][n][r2];
    }
  (void)nwq; (void)nwk; (void)fcs; (void)Kout; (void)Vout;
}

// ---------------- QKV GEMM: 4-stage counted-vmcnt pipeline (r17: depth 3->4) ----------------
// 512 threads (8 waves = 2/SIMD), 128x128 tile, BK=64, 4x32KB stage buffers (128KB,
// 1 block/CU). Lookahead-3: iter kt issues tile kt+3 (4 vmem/wave); end-of-iter waits
// vmcnt(8) (tiles kt+2,kt+3 in flight; tile kt+1 landed) + raw s_barrier + sched_barrier.
// WAR safe: stage at kt writes buf[(kt-1)%4], readers passed iter-(kt-1) barrier.
// Tail: kt==29 -> vmcnt(4), kt>=30 -> vmcnt(0). Wave grid 2x4, acc[4][2].
__global__ __launch_bounds__(512, 2) void k_gemm_qkv(
    const u16* __restrict__ A, const u16* __restrict__ BT0, const u16* __restrict__ BT1,
    u16* __restrict__ Qout, u16* __restrict__ Kout, u16* __restrict__ Vout,
    const float* __restrict__ nwq, const float* __restrict__ nwk,
    const float2* __restrict__ fcs) {
  __shared__ char lds[131072];  // 4 stages x (A 16K | B 16K)
  const int K = 2048;
  int tid = threadIdx.x, w = tid >> 6, l = tid & 63, lg = l >> 4, ll = l & 15;
  int wr = w >> 2, wc = w & 3;
  int lid = blockIdx.y * 24 + blockIdx.x;
  int xcd = lid & 7, r = lid >> 3;
  int colg = xcd & 1, rowg = xcd >> 1;
  int bxt = colg * 12 + r % 12;
  int bm0 = (rowg * 8 + r / 12) * 128;
  bool qpath = (bxt < 16);
  const u16* BT = qpath ? BT0 : BT1;
  int bn0 = qpath ? bxt * 128 : (bxt - 16) * 128;

  auto stage = [&](int si, int kt) {
    char* Sb = lds + si * 32768;
    int k0 = kt * 64;
#pragma unroll
    for (int i = 0; i < 2; i++) {
      int base = i * 512 + (w << 6);
      int c = base + l;
      int row = c >> 3, kc = (c & 7) ^ (row & 7);
      gll16(A + (size_t)(bm0 + row) * K + k0 + kc * 8, Sb + base * 16);
      gll16(BT + (size_t)(bn0 + row) * K + k0 + kc * 8, Sb + 16384 + base * 16);
    }
  };

  f32x4 acc[4][2] = {};
  stage(0, 0); stage(1, 1); stage(2, 2);
  asm volatile("s_waitcnt vmcnt(8)" ::: "memory");  // tile0 landed; tiles1,2 in flight
  __builtin_amdgcn_s_barrier();
  __builtin_amdgcn_sched_barrier(0);

  for (int kt = 0; kt < 32; ++kt) {
    int cs = kt & 3;
    if (kt + 3 < 32) stage((kt + 3) & 3, kt + 3);  // async prefetch 3 ahead
    char* As = lds + cs * 32768;
    char* Bs = As + 16384;
    __builtin_amdgcn_s_setprio(1);
#pragma unroll
    for (int ks = 0; ks < 2; ks++) {
      bf16x8 af[4], bf[2];
#pragma unroll
      for (int m = 0; m < 4; m++) {
        int row = 64 * wr + 16 * m + ll;
        af[m] = *(const bf16x8*)(As + row * 128 + (((lg + 4 * ks) ^ (row & 7)) << 4));
      }
#pragma unroll
      for (int n = 0; n < 2; n++) {
        int row = 32 * wc + 16 * n + ll;
        bf[n] = *(const bf16x8*)(Bs + row * 128 + (((lg + 4 * ks) ^ (row & 7)) << 4));
      }
#pragma unroll
      for (int m = 0; m < 4; m++)
#pragma unroll
        for (int n = 0; n < 2; n++)
          acc[m][n] = __builtin_amdgcn_mfma_f32_16x16x32_bf16(af[m], bf[n], acc[m][n], 0, 0, 0);
    }
    __builtin_amdgcn_s_setprio(0);
    if (kt <= 28) {
      asm volatile("s_waitcnt vmcnt(8)" ::: "memory");  // tile kt+1 landed
    } else if (kt == 29) {
      asm volatile("s_waitcnt vmcnt(4)" ::: "memory");  // tile 30 landed, 31 in flight
    } else {
      asm volatile("s_waitcnt vmcnt(0)" ::: "memory");  // drain
    }
    __builtin_amdgcn_s_barrier();
    __builtin_amdgcn_sched_barrier(0);
  }

  if (qpath || bn0 < 512) {
    // --- fused RMSNorm + RoPE + bf16 store (Q or K heads) ---
    const float* nw = qpath ? nwq : nwk;
    u16* O = qpath ? Qout : Kout;
    int ostride = qpath ? 2048 : 512;
    float outscale = qpath ? 0.12751744843f : 1.0f;  // log2e/sqrt(128) for Q
    float* ssum = (float*)lds;  // [wr 2][row 64][wc 4] f32 = 2KB (stage bufs dead)
    float ps[4][4];
#pragma unroll
    for (int m = 0; m < 4; m++)
#pragma unroll
      for (int r2 = 0; r2 < 4; r2++) {
        float p = 0.f;
#pragma unroll
        for (int n = 0; n < 2; n++) p += acc[m][n][r2] * acc[m][n][r2];
#pragma unroll
        for (int msk = 1; msk < 16; msk <<= 1) p += __shfl_xor(p, msk);
        ps[m][r2] = p;
      }
    if (ll == 0) {
#pragma unroll
      for (int m = 0; m < 4; m++)
#pragma unroll
        for (int r2 = 0; r2 < 4; r2++)
          ssum[wr * 256 + (16 * m + 4 * lg + r2) * 4 + wc] = ps[m][r2];
    }
    __syncthreads();
    float rs[4][4];
#pragma unroll
    for (int m = 0; m < 4; m++)
#pragma unroll
      for (int r2 = 0; r2 < 4; r2++) {
        int rowl = 16 * m + 4 * lg + r2;
        const float* sp = ssum + wr * 256 + rowl * 4;
        float tot = sp[0] + sp[1] + sp[2] + sp[3];
        rs[m][r2] = rsqrtf(tot * (1.0f / 128.0f) + 1e-5f) * outscale;
      }
#pragma unroll
    for (int m = 0; m < 4; m++)
#pragma unroll
      for (int n = 0; n < 2; n++) {
        int col = bn0 + 32 * wc + 16 * n + ll;
        int d = col & 127;
        float wgt = nw[d];
        int i = d >> 1;
#pragma unroll
        for (int r2 = 0; r2 < 4; r2++) {
          int row = bm0 + 64 * wr + 16 * m + 4 * lg + r2;
          int t = row & 2047;
          float y = acc[m][n][r2] * rs[m][r2] * wgt;
          float p = __shfl_xor(y, 1);
          float2 cs2 = fcs[t * 64 + i];
          float o = (ll & 1) ? (p * cs2.y + y * cs2.x) : (y * cs2.x - p * cs2.y);
          O[(size_t)row * ostride + col] = f2bf(o);
        }
      }
  } else {
    // --- V: bf16 + transpose to (b,kvh,d,t) via swizzled LDS ---
    int b = bm0 >> 11, t0g = bm0 & 2047;
    int kvh = (bn0 - 512) >> 7;
    int bk = b * 4 + kvh;
#pragma unroll
    for (int m = 0; m < 4; m++)
#pragma unroll
      for (int n = 0; n < 2; n++) {
        int d = 32 * wc + 16 * n + ll;
        int tloc = 64 * wr + 16 * m + 4 * lg;
        u32 w0 = pk2(acc[m][n][0], acc[m][n][1]);
        u32 w1 = pk2(acc[m][n][2], acc[m][n][3]);
        int byte = (d * 256 + tloc * 2) ^ ((d & 7) << 4);
        *(uint2*)(lds + byte) = make_uint2(w0, w1);
      }
    __syncthreads();
    int tc = tid & 15, dbase = tid >> 4;  // dbase 0..31
#pragma unroll
    for (int pass = 0; pass < 4; pass++) {
      int d = dbase + pass * 32;
      int byte = (d * 256 + tc * 16) ^ ((d & 7) << 4);
      uint4 v = *(const uint4*)(lds + byte);
      *(uint4*)(Vout + ((size_t)(bk * 128 + d)) * 2048 + t0g + tc * 8) = v;
    }
  }
}

// ---------------- causal GQA flash attention: 3-stage counted-vmcnt (r17) ----------------
// 512 threads (8 waves = 2/SIMD, QKV-proven config), 128-row Q tile, one per block.
// 512 blocks heavy-first (qb=15 first); fid&7 -> (b,kvh) XCD grouping.
// K/V 3-stage buffers (96KB) + P 16KB = 112KB -> 1 block/CU. Lookahead-2 prefetch,
// end-of-iter vmcnt(4) (tile it+1 landed; it+2's 4 in flight) + raw s_barrier +
// sched_barrier(0). WAR: stage at it writes buf[(it-1)%3], readers passed iter-(it-1)
// barrier. Per-wave inner body identical to r15 (16 q-rows x 64 kv, proven swizzles,
// static-normalizer softmax, ones-MFMA row-sum, setprio).
__global__ __launch_bounds__(512, 2) void k_attn(
    const u16* __restrict__ Q, const u16* __restrict__ Kb,
    const u16* __restrict__ Vt, u16* __restrict__ Y) {
  __shared__ char lds[114688];  // 3 x (K 16K | V 16K) | P 16K
  char* Ps = lds + 98304;
  int tid = threadIdx.x, w = tid >> 6, l = tid & 63, lg = l >> 4, ll = l & 15;
  int fid = blockIdx.x;
  int g = fid & 7, rank = fid >> 3;   // rank 0..63
  int b = g >> 2, kvh = g & 3;
  int h = kvh * 4 + (rank & 3);
  int qb = 15 - (rank >> 2);          // heavy q-tiles dispatched first
  int q0 = qb * 128;
  const u16* Kbase = Kb + ((size_t)b * 2048) * 512 + kvh * 128;
  const u16* Vbase = Vt + ((size_t)(b * 4 + kvh) * 128) * 2048;

  const bf16x8 vones = {(short)0x3F80, (short)0x3F80, (short)0x3F80, (short)0x3F80,
                        (short)0x3F80, (short)0x3F80, (short)0x3F80, (short)0x3F80};

  bf16x8 qf[4];
  {
    int qrow = b * 2048 + q0 + 16 * w + ll;
    const u16* qp = Q + (size_t)qrow * 2048 + h * 128;
#pragma unroll
    for (int ks = 0; ks < 4; ks++) qf[ks] = *(const bf16x8*)(qp + ks * 32 + lg * 8);
  }
  f32x4 o[8] = {};
  f32x4 lacc = {};

  auto stage = [&](int si, int k0) {
    char* Kd = lds + si * 32768;
    char* Vd = Kd + 16384;
#pragma unroll
    for (int i = 0; i < 2; i++) {
      int base = i * 512 + (w << 6);
      int c = base + l;
      int dst = base * 16;
      int krow = c >> 4, ksrc = (c & 15) ^ (krow & 7);   // K tile [64][128]
      gll16(Kbase + (size_t)(k0 + krow) * 512 + ksrc * 8, Kd + dst);
      int vd = c >> 3, vsrc = (c & 7) ^ (vd & 7);        // V tile [128][64]
      gll16(Vbase + (size_t)vd * 2048 + k0 + vsrc * 8, Vd + dst);
    }
  };

  int nt = 2 * qb + 2;  // kv tiles of 64 covering [0, q0+128)
  stage(0, 0);
  stage(1, 64);
  asm volatile("s_waitcnt vmcnt(4)" ::: "memory");  // tile0 landed; tile1 in flight
  __builtin_amdgcn_s_barrier();
  __builtin_amdgcn_sched_barrier(0);

  for (int it = 0; it < nt; ++it) {
    if (it + 2 < nt) stage((it + 2) % 3, (it + 2) * 64);  // prefetch 2 ahead
    char* Ks = lds + (it % 3) * 32768;
    char* Vs = Ks + 16384;
    // S = Q K^T (per wave: 16 q-rows x 64 kv); log2e/sqrt(D) pre-folded into Q
    f32x4 s[4] = {};
    __builtin_amdgcn_s_setprio(1);
#pragma unroll
    for (int ks = 0; ks < 4; ks++) {
#pragma unroll
      for (int n = 0; n < 4; n++) {
        int row = 16 * n + ll;
        bf16x8 kf = *(const bf16x8*)(Ks + ((row * 256 + (lg + 4 * ks) * 16) ^ ((row & 7) << 4)));
        s[n] = __builtin_amdgcn_mfma_f32_16x16x32_bf16(qf[ks], kf, s[n], 0, 0, 0);
      }
    }
    __builtin_amdgcn_s_setprio(0);
    if (it >= 2 * qb) {  // diagonal tiles: causal mask
      int k0 = it * 64;
#pragma unroll
      for (int n = 0; n < 4; n++) {
        int kk = k0 + 16 * n + ll;
#pragma unroll
        for (int r = 0; r < 4; r++) {
          int qq = q0 + 16 * w + 4 * lg + r;
          if (kk > qq) s[n][r] = -1e30f;
        }
      }
    }
    // STATIC-normalizer softmax: P = exp2(s) directly (r15-proven)
#pragma unroll
    for (int r = 0; r < 4; r++) {
      int prow = 4 * lg + r;
#pragma unroll
      for (int n = 0; n < 4; n++) {
        float e = exp2f(s[n][r]);
        int byte = (w << 11) + ((prow * 128 + (16 * n + ll) * 2) ^ ((prow & 7) << 4));
        *(u16*)(Ps + byte) = f2bf_fast(e);
      }
    }
    // O += P V ; l += P 1 (row-sum on the MFMA pipe)
    __builtin_amdgcn_s_setprio(1);
#pragma unroll
    for (int ks = 0; ks < 2; ks++) {
      bf16x8 pf = *(const bf16x8*)(Ps + (w << 11) + ((ll * 128 + (lg + 4 * ks) * 16) ^ ((ll & 7) << 4)));
      lacc = __builtin_amdgcn_mfma_f32_16x16x32_bf16(pf, vones, lacc, 0, 0, 0);
#pragma unroll
      for (int n = 0; n < 8; n++) {
        int row = 16 * n + ll;
        bf16x8 vf = *(const bf16x8*)(Vs + ((row * 128 + (lg + 4 * ks) * 16) ^ ((row & 7) << 4)));
        o[n] = __builtin_amdgcn_mfma_f32_16x16x32_bf16(pf, vf, o[n], 0, 0, 0);
      }
    }
    __builtin_amdgcn_s_setprio(0);
    if (it + 2 < nt) {
      asm volatile("s_waitcnt vmcnt(4)" ::: "memory");  // tile it+1 landed
    } else {
      asm volatile("s_waitcnt vmcnt(0)" ::: "memory");  // tail drain
    }
    __builtin_amdgcn_s_barrier();
    __builtin_amdgcn_sched_barrier(0);
  }
  // output
  float rl[4];
#pragma unroll
  for (int r = 0; r < 4; r++) rl[r] = 1.0f / lacc[r];
#pragma unroll
  for (int n = 0; n < 8; n++) {
    int col = h * 128 + 16 * n + ll;
#pragma unroll
    for (int r = 0; r < 4; r++) {
      int trow = b * 2048 + q0 + 16 * w + 4 * lg + r;
      Y[(size_t)trow * 2048 + col] = f2bf_fast(o[n][r] * rl[r]);
    }
  }
}

extern "C" void kernel_launch(void* const* d_in, const int* in_sizes, int n_in,
                              void* d_out, int out_size, void* d_ws, size_t ws_size,
                              hipStream_t stream) {
  const float* x   = (const float*)d_in[0];
  const float* fc  = (const float*)d_in[1];
  const float* fs  = (const float*)d_in[2];
  const float* wq  = (const float*)d_in[3];
  const float* wk  = (const float*)d_in[4];
  const float* wv  = (const float*)d_in[5];
  const float* wo  = (const float*)d_in[6];
  const float* qnw = (const float*)d_in[7];
  const float* knw = (const float*)d_in[8];
  float* out = (float*)d_out;

  const size_t MB = 1ull << 20;
  char* ws = (char*)d_ws;
  u16*    xb   = (u16*)(ws);             // 16 MB  x bf16
  u16*    wqt  = (u16*)(ws + 16 * MB);   //  8 MB  wq^T bf16 [2048][2048]
  u16*    wkvt = (u16*)(ws + 24 * MB);   //  4 MB  [wk^T;wv^T] bf16 [1024][2048]
  u16*    wot  = (u16*)(ws + 28 * MB);   //  8 MB  wo^T bf16
  u16*    Qb   = (u16*)(ws + 36 * MB);   // 16 MB  Q' bf16 (rms+rope, x log2e/sqrt(D))
  u16*    Kbq  = (u16*)(ws + 52 * MB);   //  4 MB  K' bf16 (rms+rope)
  u16*    Vtg  = (u16*)(ws + 56 * MB);   //  4 MB  V^T bf16 (b,kvh,d,t)
  u16*    Yb   = (u16*)(ws + 60 * MB);   // 16 MB  attn out bf16
  float2* fcs  = (float2*)(ws + 76 * MB);//  1 MB  fused (cos,sin) table

  hipLaunchKernelGGL(k_prep, dim3(6720), dim3(256), 0, stream,
                     x, xb, wq, wqt, wk, wv, wkvt, wo, wot, fc, fs, fcs);
  hipLaunchKernelGGL(k_gemm_qkv, dim3(24, 32), dim3(512), 0, stream,
                     xb, wqt, wkvt, Qb, Kbq, Vtg, qnw, knw, fcs);
  hipLaunchKernelGGL(k_attn, dim3(512), dim3(512), 0, stream, Qb, Kbq, Vtg, Yb);
  hipLaunchKernelGGL((k_gemm<0>), dim3(16, 32), dim3(256), 0, stream,
                     Yb, wot, (const u16*)nullptr, (void*)out, (u16*)nullptr, (u16*)nullptr, 2048,
                     nullptr, nullptr, nullptr);
}

// Round 18
// 204.661 us; speedup vs baseline: 1.0190x; 1.0190x over previous
//
#include <hip/hip_runtime.h>
#include <hip/hip_bf16.h>

using u16 = unsigned short;
using u32 = unsigned int;

typedef short bf16x8 __attribute__((ext_vector_type(8)));
typedef float f32x4 __attribute__((ext_vector_type(4)));

#define AS1 __attribute__((address_space(1)))
#define AS3 __attribute__((address_space(3)))

__device__ __forceinline__ void gll16(const void* g, void* l) {
  __builtin_amdgcn_global_load_lds((const AS1 u32*)g, (AS3 u32*)l, 16, 0, 0);
}

__device__ __forceinline__ u16 f2bf(float x) {  // round-to-nearest-even bf16
  u32 u = __builtin_bit_cast(u32, x);
  u32 r = (u + 0x7fffu + ((u >> 16) & 1u)) >> 16;
  return (u16)r;
}
__device__ __forceinline__ u32 pk2(float lo, float hi) {
  return (u32)f2bf(lo) | ((u32)f2bf(hi) << 16);
}
__device__ __forceinline__ u16 f2bf_fast(float x) {  // hw cvt (validated r5/r6)
  __hip_bfloat16 h = __float2bfloat16(x);
  return __builtin_bit_cast(u16, h);
}

// ---------------- merged prep: x cast + 4 weight transposes + fused cos/sin table ----------------
__device__ __forceinline__ void trans64(const float* __restrict__ in, u16* __restrict__ out,
                                        int R, int Cc, int bx, int by, float (*tl)[65]) {
  int c0 = bx * 64, r0 = by * 64, tid = threadIdx.x;
#pragma unroll
  for (int i = 0; i < 16; i++) {
    int idx = i * 256 + tid; int tr = idx >> 6, tc = idx & 63;
    tl[tr][tc] = in[(size_t)(r0 + tr) * Cc + c0 + tc];
  }
  __syncthreads();
#pragma unroll
  for (int i = 0; i < 16; i++) {
    int idx = i * 256 + tid; int tr = idx >> 6, tc = idx & 63;
    out[(size_t)(c0 + tr) * R + r0 + tc] = f2bf(tl[tc][tr]);
  }
}

__global__ void k_prep(const float* __restrict__ x, u16* __restrict__ xb,
                       const float* __restrict__ wq, u16* __restrict__ wqt,
                       const float* __restrict__ wk, const float* __restrict__ wv,
                       u16* __restrict__ wkvt,
                       const float* __restrict__ wo, u16* __restrict__ wot,
                       const float* __restrict__ fc, const float* __restrict__ fs,
                       float2* __restrict__ fcs) {
  __shared__ float tl[64][65];
  int gid = blockIdx.x;
  if (gid < 4096) {
    int i = gid * 256 + threadIdx.x;
    const float4* p = (const float4*)(x + (size_t)i * 8);
    float4 a = p[0], b = p[1];
    uint4 o;
    o.x = pk2(a.x, a.y); o.y = pk2(a.z, a.w);
    o.z = pk2(b.x, b.y); o.w = pk2(b.z, b.w);
    *(uint4*)(xb + (size_t)i * 8) = o;
  } else if (gid < 5120) {
    int t = gid - 4096; trans64(wq, wqt, 2048, 2048, t & 31, t >> 5, tl);
  } else if (gid < 5376) {
    int t = gid - 5120; trans64(wk, wkvt, 2048, 512, t & 7, t >> 3, tl);
  } else if (gid < 5632) {
    int t = gid - 5376; trans64(wv, wkvt + 512 * 2048, 2048, 512, t & 7, t >> 3, tl);
  } else if (gid < 6656) {
    int t = gid - 5632; trans64(wo, wot, 2048, 2048, t & 31, t >> 5, tl);
  } else {
    int base = (gid - 6656) * 2048 + threadIdx.x * 8;
#pragma unroll
    for (int j = 0; j < 8; j++) {
      int idx = base + j;
      fcs[idx] = make_float2(fc[idx], fs[idx]);
    }
  }
}

// ---------------- QKV GEMM: 4-stage counted-vmcnt pipeline (r17-proven) ----------------
// 512 threads (8 waves = 2/SIMD), 128x128 tile, BK=64, 4x32KB stage buffers (128KB,
// 1 block/CU). Lookahead-3; end-of-iter vmcnt(8) + raw s_barrier + sched_barrier(0).
// WAR safe: stage at kt writes buf[(kt-1)%4], readers passed iter-(kt-1) barrier.
__global__ __launch_bounds__(512, 2) void k_gemm_qkv(
    const u16* __restrict__ A, const u16* __restrict__ BT0, const u16* __restrict__ BT1,
    u16* __restrict__ Qout, u16* __restrict__ Kout, u16* __restrict__ Vout,
    const float* __restrict__ nwq, const float* __restrict__ nwk,
    const float2* __restrict__ fcs) {
  __shared__ char lds[131072];  // 4 stages x (A 16K | B 16K)
  const int K = 2048;
  int tid = threadIdx.x, w = tid >> 6, l = tid & 63, lg = l >> 4, ll = l & 15;
  int wr = w >> 2, wc = w & 3;
  int lid = blockIdx.y * 24 + blockIdx.x;
  int xcd = lid & 7, r = lid >> 3;
  int colg = xcd & 1, rowg = xcd >> 1;
  int bxt = colg * 12 + r % 12;
  int bm0 = (rowg * 8 + r / 12) * 128;
  bool qpath = (bxt < 16);
  const u16* BT = qpath ? BT0 : BT1;
  int bn0 = qpath ? bxt * 128 : (bxt - 16) * 128;

  auto stage = [&](int si, int kt) {
    char* Sb = lds + si * 32768;
    int k0 = kt * 64;
#pragma unroll
    for (int i = 0; i < 2; i++) {
      int base = i * 512 + (w << 6);
      int c = base + l;
      int row = c >> 3, kc = (c & 7) ^ (row & 7);
      gll16(A + (size_t)(bm0 + row) * K + k0 + kc * 8, Sb + base * 16);
      gll16(BT + (size_t)(bn0 + row) * K + k0 + kc * 8, Sb + 16384 + base * 16);
    }
  };

  f32x4 acc[4][2] = {};
  stage(0, 0); stage(1, 1); stage(2, 2);
  asm volatile("s_waitcnt vmcnt(8)" ::: "memory");
  __builtin_amdgcn_s_barrier();
  __builtin_amdgcn_sched_barrier(0);

  for (int kt = 0; kt < 32; ++kt) {
    int cs = kt & 3;
    if (kt + 3 < 32) stage((kt + 3) & 3, kt + 3);
    char* As = lds + cs * 32768;
    char* Bs = As + 16384;
    __builtin_amdgcn_s_setprio(1);
#pragma unroll
    for (int ks = 0; ks < 2; ks++) {
      bf16x8 af[4], bf[2];
#pragma unroll
      for (int m = 0; m < 4; m++) {
        int row = 64 * wr + 16 * m + ll;
        af[m] = *(const bf16x8*)(As + row * 128 + (((lg + 4 * ks) ^ (row & 7)) << 4));
      }
#pragma unroll
      for (int n = 0; n < 2; n++) {
        int row = 32 * wc + 16 * n + ll;
        bf[n] = *(const bf16x8*)(Bs + row * 128 + (((lg + 4 * ks) ^ (row & 7)) << 4));
      }
#pragma unroll
      for (int m = 0; m < 4; m++)
#pragma unroll
        for (int n = 0; n < 2; n++)
          acc[m][n] = __builtin_amdgcn_mfma_f32_16x16x32_bf16(af[m], bf[n], acc[m][n], 0, 0, 0);
    }
    __builtin_amdgcn_s_setprio(0);
    if (kt <= 28) {
      asm volatile("s_waitcnt vmcnt(8)" ::: "memory");
    } else if (kt == 29) {
      asm volatile("s_waitcnt vmcnt(4)" ::: "memory");
    } else {
      asm volatile("s_waitcnt vmcnt(0)" ::: "memory");
    }
    __builtin_amdgcn_s_barrier();
    __builtin_amdgcn_sched_barrier(0);
  }

  if (qpath || bn0 < 512) {
    const float* nw = qpath ? nwq : nwk;
    u16* O = qpath ? Qout : Kout;
    int ostride = qpath ? 2048 : 512;
    float outscale = qpath ? 0.12751744843f : 1.0f;  // log2e/sqrt(128) for Q
    float* ssum = (float*)lds;
    float ps[4][4];
#pragma unroll
    for (int m = 0; m < 4; m++)
#pragma unroll
      for (int r2 = 0; r2 < 4; r2++) {
        float p = 0.f;
#pragma unroll
        for (int n = 0; n < 2; n++) p += acc[m][n][r2] * acc[m][n][r2];
#pragma unroll
        for (int msk = 1; msk < 16; msk <<= 1) p += __shfl_xor(p, msk);
        ps[m][r2] = p;
      }
    if (ll == 0) {
#pragma unroll
      for (int m = 0; m < 4; m++)
#pragma unroll
        for (int r2 = 0; r2 < 4; r2++)
          ssum[wr * 256 + (16 * m + 4 * lg + r2) * 4 + wc] = ps[m][r2];
    }
    __syncthreads();
    float rs[4][4];
#pragma unroll
    for (int m = 0; m < 4; m++)
#pragma unroll
      for (int r2 = 0; r2 < 4; r2++) {
        int rowl = 16 * m + 4 * lg + r2;
        const float* sp = ssum + wr * 256 + rowl * 4;
        float tot = sp[0] + sp[1] + sp[2] + sp[3];
        rs[m][r2] = rsqrtf(tot * (1.0f / 128.0f) + 1e-5f) * outscale;
      }
#pragma unroll
    for (int m = 0; m < 4; m++)
#pragma unroll
      for (int n = 0; n < 2; n++) {
        int col = bn0 + 32 * wc + 16 * n + ll;
        int d = col & 127;
        float wgt = nw[d];
        int i = d >> 1;
#pragma unroll
        for (int r2 = 0; r2 < 4; r2++) {
          int row = bm0 + 64 * wr + 16 * m + 4 * lg + r2;
          int t = row & 2047;
          float y = acc[m][n][r2] * rs[m][r2] * wgt;
          float p = __shfl_xor(y, 1);
          float2 cs2 = fcs[t * 64 + i];
          float o = (ll & 1) ? (p * cs2.y + y * cs2.x) : (y * cs2.x - p * cs2.y);
          O[(size_t)row * ostride + col] = f2bf(o);
        }
      }
  } else {
    // --- V: bf16 + transpose to (b,kvh,d,t) via swizzled LDS ---
    int b = bm0 >> 11, t0g = bm0 & 2047;
    int kvh = (bn0 - 512) >> 7;
    int bk = b * 4 + kvh;
#pragma unroll
    for (int m = 0; m < 4; m++)
#pragma unroll
      for (int n = 0; n < 2; n++) {
        int d = 32 * wc + 16 * n + ll;
        int tloc = 64 * wr + 16 * m + 4 * lg;
        u32 w0 = pk2(acc[m][n][0], acc[m][n][1]);
        u32 w1 = pk2(acc[m][n][2], acc[m][n][3]);
        int byte = (d * 256 + tloc * 2) ^ ((d & 7) << 4);
        *(uint2*)(lds + byte) = make_uint2(w0, w1);
      }
    __syncthreads();
    int tc = tid & 15, dbase = tid >> 4;
#pragma unroll
    for (int pass = 0; pass < 4; pass++) {
      int d = dbase + pass * 32;
      int byte = (d * 256 + tc * 16) ^ ((d & 7) << 4);
      uint4 v = *(const uint4*)(lds + byte);
      *(uint4*)(Vout + ((size_t)(bk * 128 + d)) * 2048 + t0g + tc * 8) = v;
    }
  }
}

// ---------------- O-projection GEMM: 4-stage counted-vmcnt (r18 port of QKV template) ----------------
// 512 threads, 128x128 tile, BK=64, 4x32KB stages. Grid (16,32) XCD-rect (8bxt x 8bm).
// f32 C output. Same pipeline proof as k_gemm_qkv.
__global__ __launch_bounds__(512, 2) void k_gemm_o(
    const u16* __restrict__ A, const u16* __restrict__ BT, float* __restrict__ C) {
  __shared__ char lds[131072];
  const int K = 2048;
  int tid = threadIdx.x, w = tid >> 6, l = tid & 63, lg = l >> 4, ll = l & 15;
  int wr = w >> 2, wc = w & 3;
  int lid = blockIdx.y * 16 + blockIdx.x;
  int xcd = lid & 7, r = lid >> 3;           // r 0..63
  int colg = xcd & 1, rowg = xcd >> 1;
  int bxt = colg * 8 + r % 8;
  int bm0 = (rowg * 8 + r / 8) * 128;
  int bn0 = bxt * 128;

  auto stage = [&](int si, int kt) {
    char* Sb = lds + si * 32768;
    int k0 = kt * 64;
#pragma unroll
    for (int i = 0; i < 2; i++) {
      int base = i * 512 + (w << 6);
      int c = base + l;
      int row = c >> 3, kc = (c & 7) ^ (row & 7);
      gll16(A + (size_t)(bm0 + row) * K + k0 + kc * 8, Sb + base * 16);
      gll16(BT + (size_t)(bn0 + row) * K + k0 + kc * 8, Sb + 16384 + base * 16);
    }
  };

  f32x4 acc[4][2] = {};
  stage(0, 0); stage(1, 1); stage(2, 2);
  asm volatile("s_waitcnt vmcnt(8)" ::: "memory");
  __builtin_amdgcn_s_barrier();
  __builtin_amdgcn_sched_barrier(0);

  for (int kt = 0; kt < 32; ++kt) {
    int cs = kt & 3;
    if (kt + 3 < 32) stage((kt + 3) & 3, kt + 3);
    char* As = lds + cs * 32768;
    char* Bs = As + 16384;
    __builtin_amdgcn_s_setprio(1);
#pragma unroll
    for (int ks = 0; ks < 2; ks++) {
      bf16x8 af[4], bf[2];
#pragma unroll
      for (int m = 0; m < 4; m++) {
        int row = 64 * wr + 16 * m + ll;
        af[m] = *(const bf16x8*)(As + row * 128 + (((lg + 4 * ks) ^ (row & 7)) << 4));
      }
#pragma unroll
      for (int n = 0; n < 2; n++) {
        int row = 32 * wc + 16 * n + ll;
        bf[n] = *(const bf16x8*)(Bs + row * 128 + (((lg + 4 * ks) ^ (row & 7)) << 4));
      }
#pragma unroll
      for (int m = 0; m < 4; m++)
#pragma unroll
        for (int n = 0; n < 2; n++)
          acc[m][n] = __builtin_amdgcn_mfma_f32_16x16x32_bf16(af[m], bf[n], acc[m][n], 0, 0, 0);
    }
    __builtin_amdgcn_s_setprio(0);
    if (kt <= 28) {
      asm volatile("s_waitcnt vmcnt(8)" ::: "memory");
    } else if (kt == 29) {
      asm volatile("s_waitcnt vmcnt(4)" ::: "memory");
    } else {
      asm volatile("s_waitcnt vmcnt(0)" ::: "memory");
    }
    __builtin_amdgcn_s_barrier();
    __builtin_amdgcn_sched_barrier(0);
  }

#pragma unroll
  for (int m = 0; m < 4; m++)
#pragma unroll
    for (int n = 0; n < 2; n++) {
      int row = bm0 + 64 * wr + 16 * m + 4 * lg;
      int col = bn0 + 32 * wc + 16 * n + ll;
      float* cp = C + (size_t)row * 2048 + col;
#pragma unroll
      for (int r2 = 0; r2 < 4; r2++) cp[(size_t)r2 * 2048] = acc[m][n][r2];
    }
}

// ---------------- causal GQA flash attention (r15-proven body, verbatim) ----------------
// 512 blocks, 256 thr, 2 blocks/CU. fid&7 -> (b,kvh) XCD grouping; q-tiles {pairId,31-pairId}.
// K/V double-buffered via global_load_lds (pre-swizzled source). Static-normalizer softmax
// (P = exp2(s), normalizer cancels in (P V)/(P 1)); ones-MFMA row-sum; setprio.
// r17 lesson: attn loads are L2-resident -> 2-deep dbuf at 2 blocks/CU beats 3-stage at 1.
__global__ __launch_bounds__(256, 4) void k_attn(
    const u16* __restrict__ Q, const u16* __restrict__ Kb,
    const u16* __restrict__ Vt, u16* __restrict__ Y) {
  __shared__ char lds[73728];  // K0 16K | V0 16K | K1 16K | V1 16K | P 8K
  char* Ps = lds + 65536;
  int tid = threadIdx.x, w = tid >> 6, l = tid & 63, lg = l >> 4, ll = l & 15;
  int fid = blockIdx.x;
  int g = fid & 7, rank = fid >> 3;
  int b = g >> 2, kvh = g & 3;
  int h = kvh * 4 + (rank & 3);
  int pairId = rank >> 2;  // 0..15
  const u16* Kbase = Kb + ((size_t)b * 2048) * 512 + kvh * 128;
  const u16* Vbase = Vt + ((size_t)(b * 4 + kvh) * 128) * 2048;

  const bf16x8 vones = {(short)0x3F80, (short)0x3F80, (short)0x3F80, (short)0x3F80,
                        (short)0x3F80, (short)0x3F80, (short)0x3F80, (short)0x3F80};

#pragma unroll 1
  for (int qi = 0; qi < 2; qi++) {
    int qb = qi ? (31 - pairId) : pairId;
    int q0 = qb * 64;
    bf16x8 qf[4];
    {
      int qrow = b * 2048 + q0 + 16 * w + ll;
      const u16* qp = Q + (size_t)qrow * 2048 + h * 128;
#pragma unroll
      for (int ks = 0; ks < 4; ks++) qf[ks] = *(const bf16x8*)(qp + ks * 32 + lg * 8);
    }
    f32x4 o[8] = {};
    f32x4 lacc = {};

    auto stage = [&](int bi, int k0) {
      char* Kd = lds + (bi ? 32768 : 0);
      char* Vd = lds + (bi ? 49152 : 16384);
#pragma unroll
      for (int i = 0; i < 4; i++) {
        int c = i * 256 + tid;
        int dst = (i * 256 + (w << 6)) * 16;
        int krow = c >> 4, ksrc = (c & 15) ^ (krow & 7);
        gll16(Kbase + (size_t)(k0 + krow) * 512 + ksrc * 8, Kd + dst);
        int vd = c >> 3, vsrc = (c & 7) ^ (vd & 7);
        gll16(Vbase + (size_t)vd * 2048 + k0 + vsrc * 8, Vd + dst);
      }
    };

    stage(0, 0);
    asm volatile("s_waitcnt vmcnt(0)" ::: "memory");
    __syncthreads();

    int cur = 0;
    for (int it = 0; it <= qb; ++it) {
      if (it < qb) stage(cur ^ 1, (it + 1) * 64);
      char* Ks = lds + (cur ? 32768 : 0);
      char* Vs = lds + (cur ? 49152 : 16384);
      f32x4 s[4] = {};
      __builtin_amdgcn_s_setprio(1);
#pragma unroll
      for (int ks = 0; ks < 4; ks++) {
#pragma unroll
        for (int n = 0; n < 4; n++) {
          int row = 16 * n + ll;
          bf16x8 kf = *(const bf16x8*)(Ks + ((row * 256 + (lg + 4 * ks) * 16) ^ ((row & 7) << 4)));
          s[n] = __builtin_amdgcn_mfma_f32_16x16x32_bf16(qf[ks], kf, s[n], 0, 0, 0);
        }
      }
      __builtin_amdgcn_s_setprio(0);
      if (it == qb) {  // diagonal tile: causal mask
        int k0 = it * 64;
#pragma unroll
        for (int n = 0; n < 4; n++) {
          int kk = k0 + 16 * n + ll;
#pragma unroll
          for (int r = 0; r < 4; r++) {
            int qq = q0 + 16 * w + 4 * lg + r;
            if (kk > qq) s[n][r] = -1e30f;
          }
        }
      }
      // STATIC-normalizer softmax: P = exp2(s) directly
#pragma unroll
      for (int r = 0; r < 4; r++) {
        int prow = 4 * lg + r;
#pragma unroll
        for (int n = 0; n < 4; n++) {
          float e = exp2f(s[n][r]);
          int byte = (w << 11) + ((prow * 128 + (16 * n + ll) * 2) ^ ((prow & 7) << 4));
          *(u16*)(Ps + byte) = f2bf_fast(e);
        }
      }
      __builtin_amdgcn_s_setprio(1);
#pragma unroll
      for (int ks = 0; ks < 2; ks++) {
        bf16x8 pf = *(const bf16x8*)(Ps + (w << 11) + ((ll * 128 + (lg + 4 * ks) * 16) ^ ((ll & 7) << 4)));
        lacc = __builtin_amdgcn_mfma_f32_16x16x32_bf16(pf, vones, lacc, 0, 0, 0);
#pragma unroll
        for (int n = 0; n < 8; n++) {
          int row = 16 * n + ll;
          bf16x8 vf = *(const bf16x8*)(Vs + ((row * 128 + (lg + 4 * ks) * 16) ^ ((row & 7) << 4)));
          o[n] = __builtin_amdgcn_mfma_f32_16x16x32_bf16(pf, vf, o[n], 0, 0, 0);
        }
      }
      __builtin_amdgcn_s_setprio(0);
      asm volatile("s_waitcnt vmcnt(0)" ::: "memory");
      __syncthreads();
      cur ^= 1;
    }
    float rl[4];
#pragma unroll
    for (int r = 0; r < 4; r++) rl[r] = 1.0f / lacc[r];
#pragma unroll
    for (int n = 0; n < 8; n++) {
      int col = h * 128 + 16 * n + ll;
#pragma unroll
      for (int r = 0; r < 4; r++) {
        int trow = b * 2048 + q0 + 16 * w + 4 * lg + r;
        Y[(size_t)trow * 2048 + col] = f2bf_fast(o[n][r] * rl[r]);
      }
    }
  }
  (void)Vbase;
}

extern "C" void kernel_launch(void* const* d_in, const int* in_sizes, int n_in,
                              void* d_out, int out_size, void* d_ws, size_t ws_size,
                              hipStream_t stream) {
  const float* x   = (const float*)d_in[0];
  const float* fc  = (const float*)d_in[1];
  const float* fs  = (const float*)d_in[2];
  const float* wq  = (const float*)d_in[3];
  const float* wk  = (const float*)d_in[4];
  const float* wv  = (const float*)d_in[5];
  const float* wo  = (const float*)d_in[6];
  const float* qnw = (const float*)d_in[7];
  const float* knw = (const float*)d_in[8];
  float* out = (float*)d_out;

  const size_t MB = 1ull << 20;
  char* ws = (char*)d_ws;
  u16*    xb   = (u16*)(ws);             // 16 MB  x bf16
  u16*    wqt  = (u16*)(ws + 16 * MB);   //  8 MB  wq^T bf16 [2048][2048]
  u16*    wkvt = (u16*)(ws + 24 * MB);   //  4 MB  [wk^T;wv^T] bf16 [1024][2048]
  u16*    wot  = (u16*)(ws + 28 * MB);   //  8 MB  wo^T bf16
  u16*    Qb   = (u16*)(ws + 36 * MB);   // 16 MB  Q' bf16 (rms+rope, x log2e/sqrt(D))
  u16*    Kbq  = (u16*)(ws + 52 * MB);   //  4 MB  K' bf16 (rms+rope)
  u16*    Vtg  = (u16*)(ws + 56 * MB);   //  4 MB  V^T bf16 (b,kvh,d,t)
  u16*    Yb   = (u16*)(ws + 60 * MB);   // 16 MB  attn out bf16
  float2* fcs  = (float2*)(ws + 76 * MB);//  1 MB  fused (cos,sin) table

  hipLaunchKernelGGL(k_prep, dim3(6720), dim3(256), 0, stream,
                     x, xb, wq, wqt, wk, wv, wkvt, wo, wot, fc, fs, fcs);
  hipLaunchKernelGGL(k_gemm_qkv, dim3(24, 32), dim3(512), 0, stream,
                     xb, wqt, wkvt, Qb, Kbq, Vtg, qnw, knw, fcs);
  hipLaunchKernelGGL(k_attn, dim3(512), dim3(256), 0, stream, Qb, Kbq, Vtg, Yb);
  hipLaunchKernelGGL(k_gemm_o, dim3(16, 32), dim3(512), 0, stream, Yb, wot, out);
}

// Round 19
// 199.988 us; speedup vs baseline: 1.0428x; 1.0234x over previous
//
#include <hip/hip_runtime.h>
#include <hip/hip_bf16.h>

using u16 = unsigned short;
using u32 = unsigned int;

typedef short bf16x8 __attribute__((ext_vector_type(8)));
typedef float f32x4 __attribute__((ext_vector_type(4)));

#define AS1 __attribute__((address_space(1)))
#define AS3 __attribute__((address_space(3)))

__device__ __forceinline__ void gll16(const void* g, void* l) {
  __builtin_amdgcn_global_load_lds((const AS1 u32*)g, (AS3 u32*)l, 16, 0, 0);
}

__device__ __forceinline__ u16 f2bf(float x) {  // round-to-nearest-even bf16
  u32 u = __builtin_bit_cast(u32, x);
  u32 r = (u + 0x7fffu + ((u >> 16) & 1u)) >> 16;
  return (u16)r;
}
__device__ __forceinline__ u32 pk2(float lo, float hi) {
  return (u32)f2bf(lo) | ((u32)f2bf(hi) << 16);
}
__device__ __forceinline__ u16 f2bf_fast(float x) {  // hw cvt (validated r5/r6)
  __hip_bfloat16 h = __float2bfloat16(x);
  return __builtin_bit_cast(u16, h);
}

// ---------------- merged prep: x cast + 4 weight transposes + fused cos/sin table ----------------
__device__ __forceinline__ void trans64(const float* __restrict__ in, u16* __restrict__ out,
                                        int R, int Cc, int bx, int by, float (*tl)[65]) {
  int c0 = bx * 64, r0 = by * 64, tid = threadIdx.x;
#pragma unroll
  for (int i = 0; i < 16; i++) {
    int idx = i * 256 + tid; int tr = idx >> 6, tc = idx & 63;
    tl[tr][tc] = in[(size_t)(r0 + tr) * Cc + c0 + tc];
  }
  __syncthreads();
#pragma unroll
  for (int i = 0; i < 16; i++) {
    int idx = i * 256 + tid; int tr = idx >> 6, tc = idx & 63;
    out[(size_t)(c0 + tr) * R + r0 + tc] = f2bf(tl[tc][tr]);
  }
}

__global__ void k_prep(const float* __restrict__ x, u16* __restrict__ xb,
                       const float* __restrict__ wq, u16* __restrict__ wqt,
                       const float* __restrict__ wk, const float* __restrict__ wv,
                       u16* __restrict__ wkvt,
                       const float* __restrict__ wo, u16* __restrict__ wot,
                       const float* __restrict__ fc, const float* __restrict__ fs,
                       float2* __restrict__ fcs) {
  __shared__ float tl[64][65];
  int gid = blockIdx.x;
  if (gid < 4096) {
    int i = gid * 256 + threadIdx.x;
    const float4* p = (const float4*)(x + (size_t)i * 8);
    float4 a = p[0], b = p[1];
    uint4 o;
    o.x = pk2(a.x, a.y); o.y = pk2(a.z, a.w);
    o.z = pk2(b.x, b.y); o.w = pk2(b.z, b.w);
    *(uint4*)(xb + (size_t)i * 8) = o;
  } else if (gid < 5120) {
    int t = gid - 4096; trans64(wq, wqt, 2048, 2048, t & 31, t >> 5, tl);
  } else if (gid < 5376) {
    int t = gid - 5120; trans64(wk, wkvt, 2048, 512, t & 7, t >> 3, tl);
  } else if (gid < 5632) {
    int t = gid - 5376; trans64(wv, wkvt + 512 * 2048, 2048, 512, t & 7, t >> 3, tl);
  } else if (gid < 6656) {
    int t = gid - 5632; trans64(wo, wot, 2048, 2048, t & 31, t >> 5, tl);
  } else {
    int base = (gid - 6656) * 2048 + threadIdx.x * 8;
#pragma unroll
    for (int j = 0; j < 8; j++) {
      int idx = base + j;
      fcs[idx] = make_float2(fc[idx], fs[idx]);
    }
  }
}

// ---------------- QKV GEMM: 4-stage counted-vmcnt pipeline (r17-proven) ----------------
__global__ __launch_bounds__(512, 2) void k_gemm_qkv(
    const u16* __restrict__ A, const u16* __restrict__ BT0, const u16* __restrict__ BT1,
    u16* __restrict__ Qout, u16* __restrict__ Kout, u16* __restrict__ Vout,
    const float* __restrict__ nwq, const float* __restrict__ nwk,
    const float2* __restrict__ fcs) {
  __shared__ char lds[131072];  // 4 stages x (A 16K | B 16K)
  const int K = 2048;
  int tid = threadIdx.x, w = tid >> 6, l = tid & 63, lg = l >> 4, ll = l & 15;
  int wr = w >> 2, wc = w & 3;
  int lid = blockIdx.y * 24 + blockIdx.x;
  int xcd = lid & 7, r = lid >> 3;
  int colg = xcd & 1, rowg = xcd >> 1;
  int bxt = colg * 12 + r % 12;
  int bm0 = (rowg * 8 + r / 12) * 128;
  bool qpath = (bxt < 16);
  const u16* BT = qpath ? BT0 : BT1;
  int bn0 = qpath ? bxt * 128 : (bxt - 16) * 128;

  auto stage = [&](int si, int kt) {
    char* Sb = lds + si * 32768;
    int k0 = kt * 64;
#pragma unroll
    for (int i = 0; i < 2; i++) {
      int base = i * 512 + (w << 6);
      int c = base + l;
      int row = c >> 3, kc = (c & 7) ^ (row & 7);
      gll16(A + (size_t)(bm0 + row) * K + k0 + kc * 8, Sb + base * 16);
      gll16(BT + (size_t)(bn0 + row) * K + k0 + kc * 8, Sb + 16384 + base * 16);
    }
  };

  f32x4 acc[4][2] = {};
  stage(0, 0); stage(1, 1); stage(2, 2);
  asm volatile("s_waitcnt vmcnt(8)" ::: "memory");
  __builtin_amdgcn_s_barrier();
  __builtin_amdgcn_sched_barrier(0);

  for (int kt = 0; kt < 32; ++kt) {
    int cs = kt & 3;
    if (kt + 3 < 32) stage((kt + 3) & 3, kt + 3);
    char* As = lds + cs * 32768;
    char* Bs = As + 16384;
    __builtin_amdgcn_s_setprio(1);
#pragma unroll
    for (int ks = 0; ks < 2; ks++) {
      bf16x8 af[4], bf[2];
#pragma unroll
      for (int m = 0; m < 4; m++) {
        int row = 64 * wr + 16 * m + ll;
        af[m] = *(const bf16x8*)(As + row * 128 + (((lg + 4 * ks) ^ (row & 7)) << 4));
      }
#pragma unroll
      for (int n = 0; n < 2; n++) {
        int row = 32 * wc + 16 * n + ll;
        bf[n] = *(const bf16x8*)(Bs + row * 128 + (((lg + 4 * ks) ^ (row & 7)) << 4));
      }
#pragma unroll
      for (int m = 0; m < 4; m++)
#pragma unroll
        for (int n = 0; n < 2; n++)
          acc[m][n] = __builtin_amdgcn_mfma_f32_16x16x32_bf16(af[m], bf[n], acc[m][n], 0, 0, 0);
    }
    __builtin_amdgcn_s_setprio(0);
    if (kt <= 28) {
      asm volatile("s_waitcnt vmcnt(8)" ::: "memory");
    } else if (kt == 29) {
      asm volatile("s_waitcnt vmcnt(4)" ::: "memory");
    } else {
      asm volatile("s_waitcnt vmcnt(0)" ::: "memory");
    }
    __builtin_amdgcn_s_barrier();
    __builtin_amdgcn_sched_barrier(0);
  }

  if (qpath || bn0 < 512) {
    const float* nw = qpath ? nwq : nwk;
    u16* O = qpath ? Qout : Kout;
    int ostride = qpath ? 2048 : 512;
    float outscale = qpath ? 0.12751744843f : 1.0f;  // log2e/sqrt(128) for Q
    float* ssum = (float*)lds;
    float ps[4][4];
#pragma unroll
    for (int m = 0; m < 4; m++)
#pragma unroll
      for (int r2 = 0; r2 < 4; r2++) {
        float p = 0.f;
#pragma unroll
        for (int n = 0; n < 2; n++) p += acc[m][n][r2] * acc[m][n][r2];
#pragma unroll
        for (int msk = 1; msk < 16; msk <<= 1) p += __shfl_xor(p, msk);
        ps[m][r2] = p;
      }
    if (ll == 0) {
#pragma unroll
      for (int m = 0; m < 4; m++)
#pragma unroll
        for (int r2 = 0; r2 < 4; r2++)
          ssum[wr * 256 + (16 * m + 4 * lg + r2) * 4 + wc] = ps[m][r2];
    }
    __syncthreads();
    float rs[4][4];
#pragma unroll
    for (int m = 0; m < 4; m++)
#pragma unroll
      for (int r2 = 0; r2 < 4; r2++) {
        int rowl = 16 * m + 4 * lg + r2;
        const float* sp = ssum + wr * 256 + rowl * 4;
        float tot = sp[0] + sp[1] + sp[2] + sp[3];
        rs[m][r2] = rsqrtf(tot * (1.0f / 128.0f) + 1e-5f) * outscale;
      }
#pragma unroll
    for (int m = 0; m < 4; m++)
#pragma unroll
      for (int n = 0; n < 2; n++) {
        int col = bn0 + 32 * wc + 16 * n + ll;
        int d = col & 127;
        float wgt = nw[d];
        int i = d >> 1;
#pragma unroll
        for (int r2 = 0; r2 < 4; r2++) {
          int row = bm0 + 64 * wr + 16 * m + 4 * lg + r2;
          int t = row & 2047;
          float y = acc[m][n][r2] * rs[m][r2] * wgt;
          float p = __shfl_xor(y, 1);
          float2 cs2 = fcs[t * 64 + i];
          float o = (ll & 1) ? (p * cs2.y + y * cs2.x) : (y * cs2.x - p * cs2.y);
          O[(size_t)row * ostride + col] = f2bf(o);
        }
      }
  } else {
    int b = bm0 >> 11, t0g = bm0 & 2047;
    int kvh = (bn0 - 512) >> 7;
    int bk = b * 4 + kvh;
#pragma unroll
    for (int m = 0; m < 4; m++)
#pragma unroll
      for (int n = 0; n < 2; n++) {
        int d = 32 * wc + 16 * n + ll;
        int tloc = 64 * wr + 16 * m + 4 * lg;
        u32 w0 = pk2(acc[m][n][0], acc[m][n][1]);
        u32 w1 = pk2(acc[m][n][2], acc[m][n][3]);
        int byte = (d * 256 + tloc * 2) ^ ((d & 7) << 4);
        *(uint2*)(lds + byte) = make_uint2(w0, w1);
      }
    __syncthreads();
    int tc = tid & 15, dbase = tid >> 4;
#pragma unroll
    for (int pass = 0; pass < 4; pass++) {
      int d = dbase + pass * 32;
      int byte = (d * 256 + tc * 16) ^ ((d & 7) << 4);
      uint4 v = *(const uint4*)(lds + byte);
      *(uint4*)(Vout + ((size_t)(bk * 128 + d)) * 2048 + t0g + tc * 8) = v;
    }
  }
}

// ---------------- O-projection GEMM: 4-stage counted-vmcnt (r18-proven) ----------------
__global__ __launch_bounds__(512, 2) void k_gemm_o(
    const u16* __restrict__ A, const u16* __restrict__ BT, float* __restrict__ C) {
  __shared__ char lds[131072];
  const int K = 2048;
  int tid = threadIdx.x, w = tid >> 6, l = tid & 63, lg = l >> 4, ll = l & 15;
  int wr = w >> 2, wc = w & 3;
  int lid = blockIdx.y * 16 + blockIdx.x;
  int xcd = lid & 7, r = lid >> 3;
  int colg = xcd & 1, rowg = xcd >> 1;
  int bxt = colg * 8 + r % 8;
  int bm0 = (rowg * 8 + r / 8) * 128;
  int bn0 = bxt * 128;

  auto stage = [&](int si, int kt) {
    char* Sb = lds + si * 32768;
    int k0 = kt * 64;
#pragma unroll
    for (int i = 0; i < 2; i++) {
      int base = i * 512 + (w << 6);
      int c = base + l;
      int row = c >> 3, kc = (c & 7) ^ (row & 7);
      gll16(A + (size_t)(bm0 + row) * K + k0 + kc * 8, Sb + base * 16);
      gll16(BT + (size_t)(bn0 + row) * K + k0 + kc * 8, Sb + 16384 + base * 16);
    }
  };

  f32x4 acc[4][2] = {};
  stage(0, 0); stage(1, 1); stage(2, 2);
  asm volatile("s_waitcnt vmcnt(8)" ::: "memory");
  __builtin_amdgcn_s_barrier();
  __builtin_amdgcn_sched_barrier(0);

  for (int kt = 0; kt < 32; ++kt) {
    int cs = kt & 3;
    if (kt + 3 < 32) stage((kt + 3) & 3, kt + 3);
    char* As = lds + cs * 32768;
    char* Bs = As + 16384;
    __builtin_amdgcn_s_setprio(1);
#pragma unroll
    for (int ks = 0; ks < 2; ks++) {
      bf16x8 af[4], bf[2];
#pragma unroll
      for (int m = 0; m < 4; m++) {
        int row = 64 * wr + 16 * m + ll;
        af[m] = *(const bf16x8*)(As + row * 128 + (((lg + 4 * ks) ^ (row & 7)) << 4));
      }
#pragma unroll
      for (int n = 0; n < 2; n++) {
        int row = 32 * wc + 16 * n + ll;
        bf[n] = *(const bf16x8*)(Bs + row * 128 + (((lg + 4 * ks) ^ (row & 7)) << 4));
      }
#pragma unroll
      for (int m = 0; m < 4; m++)
#pragma unroll
        for (int n = 0; n < 2; n++)
          acc[m][n] = __builtin_amdgcn_mfma_f32_16x16x32_bf16(af[m], bf[n], acc[m][n], 0, 0, 0);
    }
    __builtin_amdgcn_s_setprio(0);
    if (kt <= 28) {
      asm volatile("s_waitcnt vmcnt(8)" ::: "memory");
    } else if (kt == 29) {
      asm volatile("s_waitcnt vmcnt(4)" ::: "memory");
    } else {
      asm volatile("s_waitcnt vmcnt(0)" ::: "memory");
    }
    __builtin_amdgcn_s_barrier();
    __builtin_amdgcn_sched_barrier(0);
  }

#pragma unroll
  for (int m = 0; m < 4; m++)
#pragma unroll
    for (int n = 0; n < 2; n++) {
      int row = bm0 + 64 * wr + 16 * m + 4 * lg;
      int col = bn0 + 32 * wc + 16 * n + ll;
      float* cp = C + (size_t)row * 2048 + col;
#pragma unroll
      for (int r2 = 0; r2 < 4; r2++) cp[(size_t)r2 * 2048] = acc[m][n][r2];
    }
}

// ---------------- causal GQA flash attention: 4-heads-share-K/V (r19) ----------------
// GQA sharing: the 4 q-heads of a kv-head run in ONE block (8 waves: wave w -> head w&3,
// row-group w>>2), so each staged K/V tile serves 128 slot-rows instead of 64 --
// staging bytes + drains per unit compute HALVE. 256 blocks (1/CU): fid&7 -> (b,kvh)
// XCD group; rank -> qt pair {rank, 63-rank} (32-row q-tiles; uniform 33 KV tiles).
// LDS: K/V dbuf 64K + P 16K = 80KB. Waves/SIMD = 2 (same as r15). Per-wave inner body
// r15-verbatim: 16 q-rows x 64 kv, proven swizzles, static softmax, ones-MFMA row-sum.
__global__ __launch_bounds__(512, 2) void k_attn(
    const u16* __restrict__ Q, const u16* __restrict__ Kb,
    const u16* __restrict__ Vt, u16* __restrict__ Y) {
  __shared__ char lds[81920];  // K0 16K | V0 16K | K1 16K | V1 16K | P 16K
  char* Ps = lds + 65536;
  int tid = threadIdx.x, w = tid >> 6, l = tid & 63, lg = l >> 4, ll = l & 15;
  int fid = blockIdx.x;
  int g = fid & 7, rank = fid >> 3;   // rank 0..31
  int b = g >> 2, kvh = g & 3;
  int h = kvh * 4 + (w & 3);          // head per wave
  int rgrp = w >> 2;                  // row-group within the 32-row tile
  const u16* Kbase = Kb + ((size_t)b * 2048) * 512 + kvh * 128;
  const u16* Vbase = Vt + ((size_t)(b * 4 + kvh) * 128) * 2048;

  const bf16x8 vones = {(short)0x3F80, (short)0x3F80, (short)0x3F80, (short)0x3F80,
                        (short)0x3F80, (short)0x3F80, (short)0x3F80, (short)0x3F80};

  auto stage = [&](int bi, int k0) {
    char* Kd = lds + (bi ? 32768 : 0);
    char* Vd = Kd + 16384;
#pragma unroll
    for (int i = 0; i < 2; i++) {
      int base = i * 512 + (w << 6);
      int c = base + l;
      int dst = base * 16;
      int krow = c >> 4, ksrc = (c & 15) ^ (krow & 7);   // K tile [64][128]
      gll16(Kbase + (size_t)(k0 + krow) * 512 + ksrc * 8, Kd + dst);
      int vd = c >> 3, vsrc = (c & 7) ^ (vd & 7);        // V tile [128][64]
      gll16(Vbase + (size_t)vd * 2048 + k0 + vsrc * 8, Vd + dst);
    }
  };

#pragma unroll 1
  for (int qi = 0; qi < 2; qi++) {
    int qt = qi ? (63 - rank) : rank;   // 32-row q-tile index
    int q0 = qt * 32;
    int nt = (qt >> 1) + 1;             // KV tiles of 64 covering [0, q0+32)
    bf16x8 qf[4];
    {
      int qrow = b * 2048 + q0 + rgrp * 16 + ll;
      const u16* qp = Q + (size_t)qrow * 2048 + h * 128;
#pragma unroll
      for (int ks = 0; ks < 4; ks++) qf[ks] = *(const bf16x8*)(qp + ks * 32 + lg * 8);
    }
    f32x4 o[8] = {};
    f32x4 lacc = {};

    stage(0, 0);
    asm volatile("s_waitcnt vmcnt(0)" ::: "memory");
    __syncthreads();

    int cur = 0;
    for (int it = 0; it < nt; ++it) {
      if (it + 1 < nt) stage(cur ^ 1, (it + 1) * 64);
      char* Ks = lds + (cur ? 32768 : 0);
      char* Vs = Ks + 16384;
      f32x4 s[4] = {};
      __builtin_amdgcn_s_setprio(1);
#pragma unroll
      for (int ks = 0; ks < 4; ks++) {
#pragma unroll
        for (int n = 0; n < 4; n++) {
          int row = 16 * n + ll;
          bf16x8 kf = *(const bf16x8*)(Ks + ((row * 256 + (lg + 4 * ks) * 16) ^ ((row & 7) << 4)));
          s[n] = __builtin_amdgcn_mfma_f32_16x16x32_bf16(qf[ks], kf, s[n], 0, 0, 0);
        }
      }
      __builtin_amdgcn_s_setprio(0);
      if (it == nt - 1) {  // diagonal tile: causal mask
        int k0 = it * 64;
#pragma unroll
        for (int n = 0; n < 4; n++) {
          int kk = k0 + 16 * n + ll;
#pragma unroll
          for (int r = 0; r < 4; r++) {
            int qq = q0 + rgrp * 16 + 4 * lg + r;
            if (kk > qq) s[n][r] = -1e30f;
          }
        }
      }
      // STATIC-normalizer softmax: P = exp2(s) directly (r15-proven)
#pragma unroll
      for (int r = 0; r < 4; r++) {
        int prow = 4 * lg + r;
#pragma unroll
        for (int n = 0; n < 4; n++) {
          float e = exp2f(s[n][r]);
          int byte = (w << 11) + ((prow * 128 + (16 * n + ll) * 2) ^ ((prow & 7) << 4));
          *(u16*)(Ps + byte) = f2bf_fast(e);
        }
      }
      // O += P V ; l += P 1 (row-sum on the MFMA pipe)
      __builtin_amdgcn_s_setprio(1);
#pragma unroll
      for (int ks = 0; ks < 2; ks++) {
        bf16x8 pf = *(const bf16x8*)(Ps + (w << 11) + ((ll * 128 + (lg + 4 * ks) * 16) ^ ((ll & 7) << 4)));
        lacc = __builtin_amdgcn_mfma_f32_16x16x32_bf16(pf, vones, lacc, 0, 0, 0);
#pragma unroll
        for (int n = 0; n < 8; n++) {
          int row = 16 * n + ll;
          bf16x8 vf = *(const bf16x8*)(Vs + ((row * 128 + (lg + 4 * ks) * 16) ^ ((row & 7) << 4)));
          o[n] = __builtin_amdgcn_mfma_f32_16x16x32_bf16(pf, vf, o[n], 0, 0, 0);
        }
      }
      __builtin_amdgcn_s_setprio(0);
      asm volatile("s_waitcnt vmcnt(0)" ::: "memory");
      __syncthreads();
      cur ^= 1;
    }
    // output
    float rl[4];
#pragma unroll
    for (int r = 0; r < 4; r++) rl[r] = 1.0f / lacc[r];
#pragma unroll
    for (int n = 0; n < 8; n++) {
      int col = h * 128 + 16 * n + ll;
#pragma unroll
      for (int r = 0; r < 4; r++) {
        int trow = b * 2048 + q0 + rgrp * 16 + 4 * lg + r;
        Y[(size_t)trow * 2048 + col] = f2bf_fast(o[n][r] * rl[r]);
      }
    }
  }
}

extern "C" void kernel_launch(void* const* d_in, const int* in_sizes, int n_in,
                              void* d_out, int out_size, void* d_ws, size_t ws_size,
                              hipStream_t stream) {
  const float* x   = (const float*)d_in[0];
  const float* fc  = (const float*)d_in[1];
  const float* fs  = (const float*)d_in[2];
  const float* wq  = (const float*)d_in[3];
  const float* wk  = (const float*)d_in[4];
  const float* wv  = (const float*)d_in[5];
  const float* wo  = (const float*)d_in[6];
  const float* qnw = (const float*)d_in[7];
  const float* knw = (const float*)d_in[8];
  float* out = (float*)d_out;

  const size_t MB = 1ull << 20;
  char* ws = (char*)d_ws;
  u16*    xb   = (u16*)(ws);             // 16 MB  x bf16
  u16*    wqt  = (u16*)(ws + 16 * MB);   //  8 MB  wq^T bf16 [2048][2048]
  u16*    wkvt = (u16*)(ws + 24 * MB);   //  4 MB  [wk^T;wv^T] bf16 [1024][2048]
  u16*    wot  = (u16*)(ws + 28 * MB);   //  8 MB  wo^T bf16
  u16*    Qb   = (u16*)(ws + 36 * MB);   // 16 MB  Q' bf16 (rms+rope, x log2e/sqrt(D))
  u16*    Kbq  = (u16*)(ws + 52 * MB);   //  4 MB  K' bf16 (rms+rope)
  u16*    Vtg  = (u16*)(ws + 56 * MB);   //  4 MB  V^T bf16 (b,kvh,d,t)
  u16*    Yb   = (u16*)(ws + 60 * MB);   // 16 MB  attn out bf16
  float2* fcs  = (float2*)(ws + 76 * MB);//  1 MB  fused (cos,sin) table

  hipLaunchKernelGGL(k_prep, dim3(6720), dim3(256), 0, stream,
                     x, xb, wq, wqt, wk, wv, wkvt, wo, wot, fc, fs, fcs);
  hipLaunchKernelGGL(k_gemm_qkv, dim3(24, 32), dim3(512), 0, stream,
                     xb, wqt, wkvt, Qb, Kbq, Vtg, qnw, knw, fcs);
  hipLaunchKernelGGL(k_attn, dim3(256), dim3(512), 0, stream, Qb, Kbq, Vtg, Yb);
  hipLaunchKernelGGL(k_gemm_o, dim3(16, 32), dim3(512), 0, stream, Yb, wot, out);
}

// Round 20
// 195.282 us; speedup vs baseline: 1.0679x; 1.0241x over previous
//
#include <hip/hip_runtime.h>
#include <hip/hip_bf16.h>

using u16 = unsigned short;
using u32 = unsigned int;

typedef short bf16x8 __attribute__((ext_vector_type(8)));
typedef float f32x4 __attribute__((ext_vector_type(4)));

#define AS1 __attribute__((address_space(1)))
#define AS3 __attribute__((address_space(3)))

__device__ __forceinline__ void gll16(const void* g, void* l) {
  __builtin_amdgcn_global_load_lds((const AS1 u32*)g, (AS3 u32*)l, 16, 0, 0);
}

__device__ __forceinline__ u16 f2bf(float x) {  // round-to-nearest-even bf16
  u32 u = __builtin_bit_cast(u32, x);
  u32 r = (u + 0x7fffu + ((u >> 16) & 1u)) >> 16;
  return (u16)r;
}
__device__ __forceinline__ u32 pk2(float lo, float hi) {
  return (u32)f2bf(lo) | ((u32)f2bf(hi) << 16);
}
__device__ __forceinline__ u16 f2bf_fast(float x) {  // hw cvt (validated r5/r6)
  __hip_bfloat16 h = __float2bfloat16(x);
  return __builtin_bit_cast(u16, h);
}

// ---------------- merged prep: x cast + 4 weight transposes + fused cos/sin table ----------------
__device__ __forceinline__ void trans64(const float* __restrict__ in, u16* __restrict__ out,
                                        int R, int Cc, int bx, int by, float (*tl)[65]) {
  int c0 = bx * 64, r0 = by * 64, tid = threadIdx.x;
#pragma unroll
  for (int i = 0; i < 16; i++) {
    int idx = i * 256 + tid; int tr = idx >> 6, tc = idx & 63;
    tl[tr][tc] = in[(size_t)(r0 + tr) * Cc + c0 + tc];
  }
  __syncthreads();
#pragma unroll
  for (int i = 0; i < 16; i++) {
    int idx = i * 256 + tid; int tr = idx >> 6, tc = idx & 63;
    out[(size_t)(c0 + tr) * R + r0 + tc] = f2bf(tl[tc][tr]);
  }
}

__global__ void k_prep(const float* __restrict__ x, u16* __restrict__ xb,
                       const float* __restrict__ wq, u16* __restrict__ wqt,
                       const float* __restrict__ wk, const float* __restrict__ wv,
                       u16* __restrict__ wkvt,
                       const float* __restrict__ wo, u16* __restrict__ wot,
                       const float* __restrict__ fc, const float* __restrict__ fs,
                       float2* __restrict__ fcs) {
  __shared__ float tl[64][65];
  int gid = blockIdx.x;
  if (gid < 4096) {
    int i = gid * 256 + threadIdx.x;
    const float4* p = (const float4*)(x + (size_t)i * 8);
    float4 a = p[0], b = p[1];
    uint4 o;
    o.x = pk2(a.x, a.y); o.y = pk2(a.z, a.w);
    o.z = pk2(b.x, b.y); o.w = pk2(b.z, b.w);
    *(uint4*)(xb + (size_t)i * 8) = o;
  } else if (gid < 5120) {
    int t = gid - 4096; trans64(wq, wqt, 2048, 2048, t & 31, t >> 5, tl);
  } else if (gid < 5376) {
    int t = gid - 5120; trans64(wk, wkvt, 2048, 512, t & 7, t >> 3, tl);
  } else if (gid < 5632) {
    int t = gid - 5376; trans64(wv, wkvt + 512 * 2048, 2048, 512, t & 7, t >> 3, tl);
  } else if (gid < 6656) {
    int t = gid - 5632; trans64(wo, wot, 2048, 2048, t & 31, t >> 5, tl);
  } else {
    int base = (gid - 6656) * 2048 + threadIdx.x * 8;
#pragma unroll
    for (int j = 0; j < 8; j++) {
      int idx = base + j;
      fcs[idx] = make_float2(fc[idx], fs[idx]);
    }
  }
}

// ---------------- QKV GEMM: 4-stage counted-vmcnt pipeline (r17-proven) ----------------
__global__ __launch_bounds__(512, 2) void k_gemm_qkv(
    const u16* __restrict__ A, const u16* __restrict__ BT0, const u16* __restrict__ BT1,
    u16* __restrict__ Qout, u16* __restrict__ Kout, u16* __restrict__ Vout,
    const float* __restrict__ nwq, const float* __restrict__ nwk,
    const float2* __restrict__ fcs) {
  __shared__ char lds[131072];  // 4 stages x (A 16K | B 16K)
  const int K = 2048;
  int tid = threadIdx.x, w = tid >> 6, l = tid & 63, lg = l >> 4, ll = l & 15;
  int wr = w >> 2, wc = w & 3;
  int lid = blockIdx.y * 24 + blockIdx.x;
  int xcd = lid & 7, r = lid >> 3;
  int colg = xcd & 1, rowg = xcd >> 1;
  int bxt = colg * 12 + r % 12;
  int bm0 = (rowg * 8 + r / 12) * 128;
  bool qpath = (bxt < 16);
  const u16* BT = qpath ? BT0 : BT1;
  int bn0 = qpath ? bxt * 128 : (bxt - 16) * 128;

  auto stage = [&](int si, int kt) {
    char* Sb = lds + si * 32768;
    int k0 = kt * 64;
#pragma unroll
    for (int i = 0; i < 2; i++) {
      int base = i * 512 + (w << 6);
      int c = base + l;
      int row = c >> 3, kc = (c & 7) ^ (row & 7);
      gll16(A + (size_t)(bm0 + row) * K + k0 + kc * 8, Sb + base * 16);
      gll16(BT + (size_t)(bn0 + row) * K + k0 + kc * 8, Sb + 16384 + base * 16);
    }
  };

  f32x4 acc[4][2] = {};
  stage(0, 0); stage(1, 1); stage(2, 2);
  asm volatile("s_waitcnt vmcnt(8)" ::: "memory");
  __builtin_amdgcn_s_barrier();
  __builtin_amdgcn_sched_barrier(0);

  for (int kt = 0; kt < 32; ++kt) {
    int cs = kt & 3;
    if (kt + 3 < 32) stage((kt + 3) & 3, kt + 3);
    char* As = lds + cs * 32768;
    char* Bs = As + 16384;
    __builtin_amdgcn_s_setprio(1);
#pragma unroll
    for (int ks = 0; ks < 2; ks++) {
      bf16x8 af[4], bf[2];
#pragma unroll
      for (int m = 0; m < 4; m++) {
        int row = 64 * wr + 16 * m + ll;
        af[m] = *(const bf16x8*)(As + row * 128 + (((lg + 4 * ks) ^ (row & 7)) << 4));
      }
#pragma unroll
      for (int n = 0; n < 2; n++) {
        int row = 32 * wc + 16 * n + ll;
        bf[n] = *(const bf16x8*)(Bs + row * 128 + (((lg + 4 * ks) ^ (row & 7)) << 4));
      }
#pragma unroll
      for (int m = 0; m < 4; m++)
#pragma unroll
        for (int n = 0; n < 2; n++)
          acc[m][n] = __builtin_amdgcn_mfma_f32_16x16x32_bf16(af[m], bf[n], acc[m][n], 0, 0, 0);
    }
    __builtin_amdgcn_s_setprio(0);
    if (kt <= 28) {
      asm volatile("s_waitcnt vmcnt(8)" ::: "memory");
    } else if (kt == 29) {
      asm volatile("s_waitcnt vmcnt(4)" ::: "memory");
    } else {
      asm volatile("s_waitcnt vmcnt(0)" ::: "memory");
    }
    __builtin_amdgcn_s_barrier();
    __builtin_amdgcn_sched_barrier(0);
  }

  if (qpath || bn0 < 512) {
    const float* nw = qpath ? nwq : nwk;
    u16* O = qpath ? Qout : Kout;
    int ostride = qpath ? 2048 : 512;
    float outscale = qpath ? 0.12751744843f : 1.0f;  // log2e/sqrt(128) for Q
    float* ssum = (float*)lds;
    float ps[4][4];
#pragma unroll
    for (int m = 0; m < 4; m++)
#pragma unroll
      for (int r2 = 0; r2 < 4; r2++) {
        float p = 0.f;
#pragma unroll
        for (int n = 0; n < 2; n++) p += acc[m][n][r2] * acc[m][n][r2];
#pragma unroll
        for (int msk = 1; msk < 16; msk <<= 1) p += __shfl_xor(p, msk);
        ps[m][r2] = p;
      }
    if (ll == 0) {
#pragma unroll
      for (int m = 0; m < 4; m++)
#pragma unroll
        for (int r2 = 0; r2 < 4; r2++)
          ssum[wr * 256 + (16 * m + 4 * lg + r2) * 4 + wc] = ps[m][r2];
    }
    __syncthreads();
    float rs[4][4];
#pragma unroll
    for (int m = 0; m < 4; m++)
#pragma unroll
      for (int r2 = 0; r2 < 4; r2++) {
        int rowl = 16 * m + 4 * lg + r2;
        const float* sp = ssum + wr * 256 + rowl * 4;
        float tot = sp[0] + sp[1] + sp[2] + sp[3];
        rs[m][r2] = rsqrtf(tot * (1.0f / 128.0f) + 1e-5f) * outscale;
      }
#pragma unroll
    for (int m = 0; m < 4; m++)
#pragma unroll
      for (int n = 0; n < 2; n++) {
        int col = bn0 + 32 * wc + 16 * n + ll;
        int d = col & 127;
        float wgt = nw[d];
        int i = d >> 1;
#pragma unroll
        for (int r2 = 0; r2 < 4; r2++) {
          int row = bm0 + 64 * wr + 16 * m + 4 * lg + r2;
          int t = row & 2047;
          float y = acc[m][n][r2] * rs[m][r2] * wgt;
          float p = __shfl_xor(y, 1);
          float2 cs2 = fcs[t * 64 + i];
          float o = (ll & 1) ? (p * cs2.y + y * cs2.x) : (y * cs2.x - p * cs2.y);
          O[(size_t)row * ostride + col] = f2bf(o);
        }
      }
  } else {
    int b = bm0 >> 11, t0g = bm0 & 2047;
    int kvh = (bn0 - 512) >> 7;
    int bk = b * 4 + kvh;
#pragma unroll
    for (int m = 0; m < 4; m++)
#pragma unroll
      for (int n = 0; n < 2; n++) {
        int d = 32 * wc + 16 * n + ll;
        int tloc = 64 * wr + 16 * m + 4 * lg;
        u32 w0 = pk2(acc[m][n][0], acc[m][n][1]);
        u32 w1 = pk2(acc[m][n][2], acc[m][n][3]);
        int byte = (d * 256 + tloc * 2) ^ ((d & 7) << 4);
        *(uint2*)(lds + byte) = make_uint2(w0, w1);
      }
    __syncthreads();
    int tc = tid & 15, dbase = tid >> 4;
#pragma unroll
    for (int pass = 0; pass < 4; pass++) {
      int d = dbase + pass * 32;
      int byte = (d * 256 + tc * 16) ^ ((d & 7) << 4);
      uint4 v = *(const uint4*)(lds + byte);
      *(uint4*)(Vout + ((size_t)(bk * 128 + d)) * 2048 + t0g + tc * 8) = v;
    }
  }
}

// ---------------- O-projection GEMM: 128x256 tile, 3-stage counted-vmcnt (r20) ----------------
// 512 threads, BM=128 BN=256 BK=64, 3x48KB stages (A 16K | B 32K) = 144KB, 1 block/CU.
// Grid (8,32) = 256 blocks = EXACTLY one dispatch round (perfect fill; r19's 2 rounds of
// 128^2 halve to 1). 6 gll16/thread/stage; lookahead-2; steady vmcnt(6); tail vmcnt(0).
// Wave grid 2(wr)x4(wc), per-wave 64x64, acc[4][4].
__global__ __launch_bounds__(512, 2) void k_gemm_o(
    const u16* __restrict__ A, const u16* __restrict__ BT, float* __restrict__ C) {
  __shared__ char lds[147456];  // 3 stages x (A 16K | B 32K)
  const int K = 2048;
  int tid = threadIdx.x, w = tid >> 6, l = tid & 63, lg = l >> 4, ll = l & 15;
  int wr = w >> 2, wc = w & 3;
  int lid = blockIdx.y * 8 + blockIdx.x;
  int xcd = lid & 7, r = lid >> 3;           // r 0..31
  int colg = xcd & 1, rowg = xcd >> 1;       // 2 colg x 4 rowg
  int bxt = colg * 4 + (r & 3);              // 8 col-tiles of 256
  int bm0 = (rowg * 8 + (r >> 2)) * 128;     // 32 row-tiles of 128
  int bn0 = bxt * 256;

  auto stage = [&](int si, int kt) {
    char* Sb = lds + si * 49152;
    int k0 = kt * 64;
#pragma unroll
    for (int i = 0; i < 2; i++) {  // A: 128x64 bf16 = 1024 chunks
      int base = i * 512 + (w << 6);
      int c = base + l;
      int row = c >> 3, kc = (c & 7) ^ (row & 7);
      gll16(A + (size_t)(bm0 + row) * K + k0 + kc * 8, Sb + base * 16);
    }
#pragma unroll
    for (int i = 0; i < 4; i++) {  // B: 256x64 bf16 = 2048 chunks
      int base = i * 512 + (w << 6);
      int c = base + l;
      int row = c >> 3, kc = (c & 7) ^ (row & 7);
      gll16(BT + (size_t)(bn0 + row) * K + k0 + kc * 8, Sb + 16384 + base * 16);
    }
  };

  f32x4 acc[4][4] = {};
  stage(0, 0); stage(1, 1);
  asm volatile("s_waitcnt vmcnt(6)" ::: "memory");  // stage0 landed; stage1 in flight
  __builtin_amdgcn_s_barrier();
  __builtin_amdgcn_sched_barrier(0);

  for (int kt = 0; kt < 32; ++kt) {
    int cs = kt % 3;
    if (kt + 2 < 32) stage((kt + 2) % 3, kt + 2);
    char* As = lds + cs * 49152;
    char* Bs = As + 16384;
    __builtin_amdgcn_s_setprio(1);
#pragma unroll
    for (int ks = 0; ks < 2; ks++) {
      bf16x8 af[4], bf[4];
#pragma unroll
      for (int m = 0; m < 4; m++) {
        int row = 64 * wr + 16 * m + ll;
        af[m] = *(const bf16x8*)(As + row * 128 + (((lg + 4 * ks) ^ (row & 7)) << 4));
      }
#pragma unroll
      for (int n = 0; n < 4; n++) {
        int row = 64 * wc + 16 * n + ll;
        bf[n] = *(const bf16x8*)(Bs + row * 128 + (((lg + 4 * ks) ^ (row & 7)) << 4));
      }
#pragma unroll
      for (int m = 0; m < 4; m++)
#pragma unroll
        for (int n = 0; n < 4; n++)
          acc[m][n] = __builtin_amdgcn_mfma_f32_16x16x32_bf16(af[m], bf[n], acc[m][n], 0, 0, 0);
    }
    __builtin_amdgcn_s_setprio(0);
    if (kt + 2 < 32) {
      asm volatile("s_waitcnt vmcnt(6)" ::: "memory");  // stage kt+1 landed
    } else {
      asm volatile("s_waitcnt vmcnt(0)" ::: "memory");  // tail drain
    }
    __builtin_amdgcn_s_barrier();
    __builtin_amdgcn_sched_barrier(0);
  }

#pragma unroll
  for (int m = 0; m < 4; m++)
#pragma unroll
    for (int n = 0; n < 4; n++) {
      int row = bm0 + 64 * wr + 16 * m + 4 * lg;
      int col = bn0 + 64 * wc + 16 * n + ll;
      float* cp = C + (size_t)row * 2048 + col;
#pragma unroll
      for (int r2 = 0; r2 < 4; r2++) cp[(size_t)r2 * 2048] = acc[m][n][r2];
    }
}

// ---------------- causal GQA flash attention: 4-heads-share-K/V (r19-proven) ----------------
__global__ __launch_bounds__(512, 2) void k_attn(
    const u16* __restrict__ Q, const u16* __restrict__ Kb,
    const u16* __restrict__ Vt, u16* __restrict__ Y) {
  __shared__ char lds[81920];  // K0 16K | V0 16K | K1 16K | V1 16K | P 16K
  char* Ps = lds + 65536;
  int tid = threadIdx.x, w = tid >> 6, l = tid & 63, lg = l >> 4, ll = l & 15;
  int fid = blockIdx.x;
  int g = fid & 7, rank = fid >> 3;   // rank 0..31
  int b = g >> 2, kvh = g & 3;
  int h = kvh * 4 + (w & 3);          // head per wave
  int rgrp = w >> 2;                  // row-group within the 32-row tile
  const u16* Kbase = Kb + ((size_t)b * 2048) * 512 + kvh * 128;
  const u16* Vbase = Vt + ((size_t)(b * 4 + kvh) * 128) * 2048;

  const bf16x8 vones = {(short)0x3F80, (short)0x3F80, (short)0x3F80, (short)0x3F80,
                        (short)0x3F80, (short)0x3F80, (short)0x3F80, (short)0x3F80};

  auto stage = [&](int bi, int k0) {
    char* Kd = lds + (bi ? 32768 : 0);
    char* Vd = Kd + 16384;
#pragma unroll
    for (int i = 0; i < 2; i++) {
      int base = i * 512 + (w << 6);
      int c = base + l;
      int dst = base * 16;
      int krow = c >> 4, ksrc = (c & 15) ^ (krow & 7);   // K tile [64][128]
      gll16(Kbase + (size_t)(k0 + krow) * 512 + ksrc * 8, Kd + dst);
      int vd = c >> 3, vsrc = (c & 7) ^ (vd & 7);        // V tile [128][64]
      gll16(Vbase + (size_t)vd * 2048 + k0 + vsrc * 8, Vd + dst);
    }
  };

#pragma unroll 1
  for (int qi = 0; qi < 2; qi++) {
    int qt = qi ? (63 - rank) : rank;   // 32-row q-tile index
    int q0 = qt * 32;
    int nt = (qt >> 1) + 1;             // KV tiles of 64 covering [0, q0+32)
    bf16x8 qf[4];
    {
      int qrow = b * 2048 + q0 + rgrp * 16 + ll;
      const u16* qp = Q + (size_t)qrow * 2048 + h * 128;
#pragma unroll
      for (int ks = 0; ks < 4; ks++) qf[ks] = *(const bf16x8*)(qp + ks * 32 + lg * 8);
    }
    f32x4 o[8] = {};
    f32x4 lacc = {};

    stage(0, 0);
    asm volatile("s_waitcnt vmcnt(0)" ::: "memory");
    __syncthreads();

    int cur = 0;
    for (int it = 0; it < nt; ++it) {
      if (it + 1 < nt) stage(cur ^ 1, (it + 1) * 64);
      char* Ks = lds + (cur ? 32768 : 0);
      char* Vs = Ks + 16384;
      f32x4 s[4] = {};
      __builtin_amdgcn_s_setprio(1);
#pragma unroll
      for (int ks = 0; ks < 4; ks++) {
#pragma unroll
        for (int n = 0; n < 4; n++) {
          int row = 16 * n + ll;
          bf16x8 kf = *(const bf16x8*)(Ks + ((row * 256 + (lg + 4 * ks) * 16) ^ ((row & 7) << 4)));
          s[n] = __builtin_amdgcn_mfma_f32_16x16x32_bf16(qf[ks], kf, s[n], 0, 0, 0);
        }
      }
      __builtin_amdgcn_s_setprio(0);
      if (it == nt - 1) {  // diagonal tile: causal mask
        int k0 = it * 64;
#pragma unroll
        for (int n = 0; n < 4; n++) {
          int kk = k0 + 16 * n + ll;
#pragma unroll
          for (int r = 0; r < 4; r++) {
            int qq = q0 + rgrp * 16 + 4 * lg + r;
            if (kk > qq) s[n][r] = -1e30f;
          }
        }
      }
      // STATIC-normalizer softmax: P = exp2(s) directly (r15-proven)
#pragma unroll
      for (int r = 0; r < 4; r++) {
        int prow = 4 * lg + r;
#pragma unroll
        for (int n = 0; n < 4; n++) {
          float e = exp2f(s[n][r]);
          int byte = (w << 11) + ((prow * 128 + (16 * n + ll) * 2) ^ ((prow & 7) << 4));
          *(u16*)(Ps + byte) = f2bf_fast(e);
        }
      }
      // O += P V ; l += P 1 (row-sum on the MFMA pipe)
      __builtin_amdgcn_s_setprio(1);
#pragma unroll
      for (int ks = 0; ks < 2; ks++) {
        bf16x8 pf = *(const bf16x8*)(Ps + (w << 11) + ((ll * 128 + (lg + 4 * ks) * 16) ^ ((ll & 7) << 4)));
        lacc = __builtin_amdgcn_mfma_f32_16x16x32_bf16(pf, vones, lacc, 0, 0, 0);
#pragma unroll
        for (int n = 0; n < 8; n++) {
          int row = 16 * n + ll;
          bf16x8 vf = *(const bf16x8*)(Vs + ((row * 128 + (lg + 4 * ks) * 16) ^ ((row & 7) << 4)));
          o[n] = __builtin_amdgcn_mfma_f32_16x16x32_bf16(pf, vf, o[n], 0, 0, 0);
        }
      }
      __builtin_amdgcn_s_setprio(0);
      asm volatile("s_waitcnt vmcnt(0)" ::: "memory");
      __syncthreads();
      cur ^= 1;
    }
    // output
    float rl[4];
#pragma unroll
    for (int r = 0; r < 4; r++) rl[r] = 1.0f / lacc[r];
#pragma unroll
    for (int n = 0; n < 8; n++) {
      int col = h * 128 + 16 * n + ll;
#pragma unroll
      for (int r = 0; r < 4; r++) {
        int trow = b * 2048 + q0 + rgrp * 16 + 4 * lg + r;
        Y[(size_t)trow * 2048 + col] = f2bf_fast(o[n][r] * rl[r]);
      }
    }
  }
}

extern "C" void kernel_launch(void* const* d_in, const int* in_sizes, int n_in,
                              void* d_out, int out_size, void* d_ws, size_t ws_size,
                              hipStream_t stream) {
  const float* x   = (const float*)d_in[0];
  const float* fc  = (const float*)d_in[1];
  const float* fs  = (const float*)d_in[2];
  const float* wq  = (const float*)d_in[3];
  const float* wk  = (const float*)d_in[4];
  const float* wv  = (const float*)d_in[5];
  const float* wo  = (const float*)d_in[6];
  const float* qnw = (const float*)d_in[7];
  const float* knw = (const float*)d_in[8];
  float* out = (float*)d_out;

  const size_t MB = 1ull << 20;
  char* ws = (char*)d_ws;
  u16*    xb   = (u16*)(ws);             // 16 MB  x bf16
  u16*    wqt  = (u16*)(ws + 16 * MB);   //  8 MB  wq^T bf16 [2048][2048]
  u16*    wkvt = (u16*)(ws + 24 * MB);   //  4 MB  [wk^T;wv^T] bf16 [1024][2048]
  u16*    wot  = (u16*)(ws + 28 * MB);   //  8 MB  wo^T bf16
  u16*    Qb   = (u16*)(ws + 36 * MB);   // 16 MB  Q' bf16 (rms+rope, x log2e/sqrt(D))
  u16*    Kbq  = (u16*)(ws + 52 * MB);   //  4 MB  K' bf16 (rms+rope)
  u16*    Vtg  = (u16*)(ws + 56 * MB);   //  4 MB  V^T bf16 (b,kvh,d,t)
  u16*    Yb   = (u16*)(ws + 60 * MB);   // 16 MB  attn out bf16
  float2* fcs  = (float2*)(ws + 76 * MB);//  1 MB  fused (cos,sin) table

  hipLaunchKernelGGL(k_prep, dim3(6720), dim3(256), 0, stream,
                     x, xb, wq, wqt, wk, wv, wkvt, wo, wot, fc, fs, fcs);
  hipLaunchKernelGGL(k_gemm_qkv, dim3(24, 32), dim3(512), 0, stream,
                     xb, wqt, wkvt, Qb, Kbq, Vtg, qnw, knw, fcs);
  hipLaunchKernelGGL(k_attn, dim3(256), dim3(512), 0, stream, Qb, Kbq, Vtg, Yb);
  hipLaunchKernelGGL(k_gemm_o, dim3(8, 32), dim3(512), 0, stream, Yb, wot, out);
}

// Round 21
// 186.050 us; speedup vs baseline: 1.1209x; 1.0496x over previous
//
#include <hip/hip_runtime.h>
#include <hip/hip_bf16.h>

using u16 = unsigned short;
using u32 = unsigned int;

typedef short bf16x8 __attribute__((ext_vector_type(8)));
typedef float f32x4 __attribute__((ext_vector_type(4)));

#define AS1 __attribute__((address_space(1)))
#define AS3 __attribute__((address_space(3)))

__device__ __forceinline__ void gll16(const void* g, void* l) {
  __builtin_amdgcn_global_load_lds((const AS1 u32*)g, (AS3 u32*)l, 16, 0, 0);
}

__device__ __forceinline__ u16 f2bf(float x) {  // round-to-nearest-even bf16
  u32 u = __builtin_bit_cast(u32, x);
  u32 r = (u + 0x7fffu + ((u >> 16) & 1u)) >> 16;
  return (u16)r;
}
__device__ __forceinline__ u32 pk2(float lo, float hi) {
  return (u32)f2bf(lo) | ((u32)f2bf(hi) << 16);
}
__device__ __forceinline__ u16 f2bf_fast(float x) {  // hw cvt (validated r5/r6)
  __hip_bfloat16 h = __float2bfloat16(x);
  return __builtin_bit_cast(u16, h);
}

// ---------------- merged prep: x cast + 4 weight transposes + fused cos/sin table ----------------
__device__ __forceinline__ void trans64(const float* __restrict__ in, u16* __restrict__ out,
                                        int R, int Cc, int bx, int by, float (*tl)[65]) {
  int c0 = bx * 64, r0 = by * 64, tid = threadIdx.x;
#pragma unroll
  for (int i = 0; i < 16; i++) {
    int idx = i * 256 + tid; int tr = idx >> 6, tc = idx & 63;
    tl[tr][tc] = in[(size_t)(r0 + tr) * Cc + c0 + tc];
  }
  __syncthreads();
#pragma unroll
  for (int i = 0; i < 16; i++) {
    int idx = i * 256 + tid; int tr = idx >> 6, tc = idx & 63;
    out[(size_t)(c0 + tr) * R + r0 + tc] = f2bf(tl[tc][tr]);
  }
}

__global__ void k_prep(const float* __restrict__ x, u16* __restrict__ xb,
                       const float* __restrict__ wq, u16* __restrict__ wqt,
                       const float* __restrict__ wk, const float* __restrict__ wv,
                       u16* __restrict__ wkvt,
                       const float* __restrict__ wo, u16* __restrict__ wot,
                       const float* __restrict__ fc, const float* __restrict__ fs,
                       float2* __restrict__ fcs) {
  __shared__ float tl[64][65];
  int gid = blockIdx.x;
  if (gid < 4096) {
    int i = gid * 256 + threadIdx.x;
    const float4* p = (const float4*)(x + (size_t)i * 8);
    float4 a = p[0], b = p[1];
    uint4 o;
    o.x = pk2(a.x, a.y); o.y = pk2(a.z, a.w);
    o.z = pk2(b.x, b.y); o.w = pk2(b.z, b.w);
    *(uint4*)(xb + (size_t)i * 8) = o;
  } else if (gid < 5120) {
    int t = gid - 4096; trans64(wq, wqt, 2048, 2048, t & 31, t >> 5, tl);
  } else if (gid < 5376) {
    int t = gid - 5120; trans64(wk, wkvt, 2048, 512, t & 7, t >> 3, tl);
  } else if (gid < 5632) {
    int t = gid - 5376; trans64(wv, wkvt + 512 * 2048, 2048, 512, t & 7, t >> 3, tl);
  } else if (gid < 6656) {
    int t = gid - 5632; trans64(wo, wot, 2048, 2048, t & 31, t >> 5, tl);
  } else {
    int base = (gid - 6656) * 2048 + threadIdx.x * 8;
#pragma unroll
    for (int j = 0; j < 8; j++) {
      int idx = base + j;
      fcs[idx] = make_float2(fc[idx], fs[idx]);
    }
  }
}

// ---------------- QKV GEMM: heterogeneous tiles (r21) ----------------
// 512 blocks, 512 thr. Blocks 0..255 (HEAVY, dispatched first): Q projection with
// BN=256 tiles (r20 O-proj loop: 3x48KB stages, vmcnt(6), acc[4][4]) + rms/rope
// epilogue paired per 128-col head. Blocks 256..511 (LIGHT): K/V with BN=128
// (r17 loop: 4x32KB, vmcnt(8), acc[4][2]). Packing: each CU runs 1 heavy then
// 1 light backfill -> per-CU time Th+Tl < 3 uniform rounds (Q at 256-wide
// efficiency). Both halves XCD-rect remapped.
__global__ __launch_bounds__(512, 2) void k_gemm_qkv(
    const u16* __restrict__ A, const u16* __restrict__ BT0, const u16* __restrict__ BT1,
    u16* __restrict__ Qout, u16* __restrict__ Kout, u16* __restrict__ Vout,
    const float* __restrict__ nwq, const float* __restrict__ nwk,
    const float2* __restrict__ fcs) {
  __shared__ char lds[147456];
  const int K = 2048;
  int tid = threadIdx.x, w = tid >> 6, l = tid & 63, lg = l >> 4, ll = l & 15;
  int bid = blockIdx.x;

  if (bid < 256) {
    // ---------- HEAVY: Q, BN=256, 3-stage counted-vmcnt ----------
    int wr = w >> 2, wc = w & 3;
    int xcd = bid & 7, r = bid >> 3;          // r 0..31
    int colg = xcd & 1, rowg = xcd >> 1;
    int bxt = colg * 4 + (r & 3);             // 8 col-tiles of 256
    int bm0 = (rowg * 8 + (r >> 2)) * 128;    // 32 row-tiles
    int bn0 = bxt * 256;

    auto stage = [&](int si, int kt) {
      char* Sb = lds + si * 49152;
      int k0 = kt * 64;
#pragma unroll
      for (int i = 0; i < 2; i++) {  // A 128x64
        int base = i * 512 + (w << 6);
        int c = base + l;
        int row = c >> 3, kc = (c & 7) ^ (row & 7);
        gll16(A + (size_t)(bm0 + row) * K + k0 + kc * 8, Sb + base * 16);
      }
#pragma unroll
      for (int i = 0; i < 4; i++) {  // B 256x64
        int base = i * 512 + (w << 6);
        int c = base + l;
        int row = c >> 3, kc = (c & 7) ^ (row & 7);
        gll16(BT0 + (size_t)(bn0 + row) * K + k0 + kc * 8, Sb + 16384 + base * 16);
      }
    };

    f32x4 acc[4][4] = {};
    stage(0, 0); stage(1, 1);
    asm volatile("s_waitcnt vmcnt(6)" ::: "memory");
    __builtin_amdgcn_s_barrier();
    __builtin_amdgcn_sched_barrier(0);

    for (int kt = 0; kt < 32; ++kt) {
      int cs = kt % 3;
      if (kt + 2 < 32) stage((kt + 2) % 3, kt + 2);
      char* As = lds + cs * 49152;
      char* Bs = As + 16384;
      __builtin_amdgcn_s_setprio(1);
#pragma unroll
      for (int ks = 0; ks < 2; ks++) {
        bf16x8 af[4], bf[4];
#pragma unroll
        for (int m = 0; m < 4; m++) {
          int row = 64 * wr + 16 * m + ll;
          af[m] = *(const bf16x8*)(As + row * 128 + (((lg + 4 * ks) ^ (row & 7)) << 4));
        }
#pragma unroll
        for (int n = 0; n < 4; n++) {
          int row = 64 * wc + 16 * n + ll;
          bf[n] = *(const bf16x8*)(Bs + row * 128 + (((lg + 4 * ks) ^ (row & 7)) << 4));
        }
#pragma unroll
        for (int m = 0; m < 4; m++)
#pragma unroll
          for (int n = 0; n < 4; n++)
            acc[m][n] = __builtin_amdgcn_mfma_f32_16x16x32_bf16(af[m], bf[n], acc[m][n], 0, 0, 0);
      }
      __builtin_amdgcn_s_setprio(0);
      if (kt + 2 < 32) {
        asm volatile("s_waitcnt vmcnt(6)" ::: "memory");
      } else {
        asm volatile("s_waitcnt vmcnt(0)" ::: "memory");
      }
      __builtin_amdgcn_s_barrier();
      __builtin_amdgcn_sched_barrier(0);
    }

    // --- Q epilogue: rmsnorm per 128-col head (wc pairs {0,1},{2,3}) + rope ---
    float* ssum = (float*)lds;  // [wr 2][row 64][wc 4]
    float ps[4][4];
#pragma unroll
    for (int m = 0; m < 4; m++)
#pragma unroll
      for (int r2 = 0; r2 < 4; r2++) {
        float p = 0.f;
#pragma unroll
        for (int n = 0; n < 4; n++) p += acc[m][n][r2] * acc[m][n][r2];
#pragma unroll
        for (int msk = 1; msk < 16; msk <<= 1) p += __shfl_xor(p, msk);
        ps[m][r2] = p;
      }
    if (ll == 0) {
#pragma unroll
      for (int m = 0; m < 4; m++)
#pragma unroll
        for (int r2 = 0; r2 < 4; r2++)
          ssum[wr * 256 + (16 * m + 4 * lg + r2) * 4 + wc] = ps[m][r2];
    }
    __syncthreads();
    int pbase = (wc < 2) ? 0 : 2;  // head pairing within the 256-wide tile
    float rs[4][4];
#pragma unroll
    for (int m = 0; m < 4; m++)
#pragma unroll
      for (int r2 = 0; r2 < 4; r2++) {
        int rowl = 16 * m + 4 * lg + r2;
        const float* sp = ssum + wr * 256 + rowl * 4;
        float tot = sp[pbase] + sp[pbase + 1];
        rs[m][r2] = rsqrtf(tot * (1.0f / 128.0f) + 1e-5f) * 0.12751744843f;  // log2e/sqrt(128)
      }
#pragma unroll
    for (int m = 0; m < 4; m++)
#pragma unroll
      for (int n = 0; n < 4; n++) {
        int col = bn0 + 64 * wc + 16 * n + ll;
        int d = col & 127;
        float wgt = nwq[d];
        int i = d >> 1;
#pragma unroll
        for (int r2 = 0; r2 < 4; r2++) {
          int row = bm0 + 64 * wr + 16 * m + 4 * lg + r2;
          int t = row & 2047;
          float y = acc[m][n][r2] * rs[m][r2] * wgt;
          float p = __shfl_xor(y, 1);
          float2 cs2 = fcs[t * 64 + i];
          float o = (ll & 1) ? (p * cs2.y + y * cs2.x) : (y * cs2.x - p * cs2.y);
          Qout[(size_t)row * 2048 + col] = f2bf(o);
        }
      }
  } else {
    // ---------- LIGHT: K/V, BN=128, 4-stage counted-vmcnt (r17-proven) ----------
    int wr = w >> 2, wc = w & 3;
    int lid = bid - 256;
    int xcd = lid & 7, r = lid >> 3;          // r 0..31
    int colg = xcd & 1, rowg = xcd >> 1;
    int bxt = colg * 4 + (r & 3);             // 8 col-tiles of 128 within KV
    int bm0 = (rowg * 8 + (r >> 2)) * 128;
    int bn0 = bxt * 128;                      // 0..1023 within [wk^T;wv^T]
    bool kpath = (bn0 < 512);

    auto stage = [&](int si, int kt) {
      char* Sb = lds + si * 32768;
      int k0 = kt * 64;
#pragma unroll
      for (int i = 0; i < 2; i++) {
        int base = i * 512 + (w << 6);
        int c = base + l;
        int row = c >> 3, kc = (c & 7) ^ (row & 7);
        gll16(A + (size_t)(bm0 + row) * K + k0 + kc * 8, Sb + base * 16);
        gll16(BT1 + (size_t)(bn0 + row) * K + k0 + kc * 8, Sb + 16384 + base * 16);
      }
    };

    f32x4 acc[4][2] = {};
    stage(0, 0); stage(1, 1); stage(2, 2);
    asm volatile("s_waitcnt vmcnt(8)" ::: "memory");
    __builtin_amdgcn_s_barrier();
    __builtin_amdgcn_sched_barrier(0);

    for (int kt = 0; kt < 32; ++kt) {
      int cs = kt & 3;
      if (kt + 3 < 32) stage((kt + 3) & 3, kt + 3);
      char* As = lds + cs * 32768;
      char* Bs = As + 16384;
      __builtin_amdgcn_s_setprio(1);
#pragma unroll
      for (int ks = 0; ks < 2; ks++) {
        bf16x8 af[4], bf[2];
#pragma unroll
        for (int m = 0; m < 4; m++) {
          int row = 64 * wr + 16 * m + ll;
          af[m] = *(const bf16x8*)(As + row * 128 + (((lg + 4 * ks) ^ (row & 7)) << 4));
        }
#pragma unroll
        for (int n = 0; n < 2; n++) {
          int row = 32 * wc + 16 * n + ll;
          bf[n] = *(const bf16x8*)(Bs + row * 128 + (((lg + 4 * ks) ^ (row & 7)) << 4));
        }
#pragma unroll
        for (int m = 0; m < 4; m++)
#pragma unroll
          for (int n = 0; n < 2; n++)
            acc[m][n] = __builtin_amdgcn_mfma_f32_16x16x32_bf16(af[m], bf[n], acc[m][n], 0, 0, 0);
      }
      __builtin_amdgcn_s_setprio(0);
      if (kt <= 28) {
        asm volatile("s_waitcnt vmcnt(8)" ::: "memory");
      } else if (kt == 29) {
        asm volatile("s_waitcnt vmcnt(4)" ::: "memory");
      } else {
        asm volatile("s_waitcnt vmcnt(0)" ::: "memory");
      }
      __builtin_amdgcn_s_barrier();
      __builtin_amdgcn_sched_barrier(0);
    }

    if (kpath) {
      // --- K: rmsnorm + rope -> Kout ---
      float* ssum = (float*)lds;
      float ps[4][4];
#pragma unroll
      for (int m = 0; m < 4; m++)
#pragma unroll
        for (int r2 = 0; r2 < 4; r2++) {
          float p = 0.f;
#pragma unroll
          for (int n = 0; n < 2; n++) p += acc[m][n][r2] * acc[m][n][r2];
#pragma unroll
          for (int msk = 1; msk < 16; msk <<= 1) p += __shfl_xor(p, msk);
          ps[m][r2] = p;
        }
      if (ll == 0) {
#pragma unroll
        for (int m = 0; m < 4; m++)
#pragma unroll
          for (int r2 = 0; r2 < 4; r2++)
            ssum[wr * 256 + (16 * m + 4 * lg + r2) * 4 + wc] = ps[m][r2];
      }
      __syncthreads();
      float rs[4][4];
#pragma unroll
      for (int m = 0; m < 4; m++)
#pragma unroll
        for (int r2 = 0; r2 < 4; r2++) {
          int rowl = 16 * m + 4 * lg + r2;
          const float* sp = ssum + wr * 256 + rowl * 4;
          float tot = sp[0] + sp[1] + sp[2] + sp[3];
          rs[m][r2] = rsqrtf(tot * (1.0f / 128.0f) + 1e-5f);
        }
#pragma unroll
      for (int m = 0; m < 4; m++)
#pragma unroll
        for (int n = 0; n < 2; n++) {
          int col = bn0 + 32 * wc + 16 * n + ll;
          int d = col & 127;
          float wgt = nwk[d];
          int i = d >> 1;
#pragma unroll
          for (int r2 = 0; r2 < 4; r2++) {
            int row = bm0 + 64 * wr + 16 * m + 4 * lg + r2;
            int t = row & 2047;
            float y = acc[m][n][r2] * rs[m][r2] * wgt;
            float p = __shfl_xor(y, 1);
            float2 cs2 = fcs[t * 64 + i];
            float o = (ll & 1) ? (p * cs2.y + y * cs2.x) : (y * cs2.x - p * cs2.y);
            Kout[(size_t)row * 512 + col] = f2bf(o);
          }
        }
    } else {
      // --- V: bf16 + transpose to (b,kvh,d,t) via swizzled LDS ---
      int b = bm0 >> 11, t0g = bm0 & 2047;
      int kvh = (bn0 - 512) >> 7;
      int bk = b * 4 + kvh;
#pragma unroll
      for (int m = 0; m < 4; m++)
#pragma unroll
        for (int n = 0; n < 2; n++) {
          int d = 32 * wc + 16 * n + ll;
          int tloc = 64 * wr + 16 * m + 4 * lg;
          u32 w0 = pk2(acc[m][n][0], acc[m][n][1]);
          u32 w1 = pk2(acc[m][n][2], acc[m][n][3]);
          int byte = (d * 256 + tloc * 2) ^ ((d & 7) << 4);
          *(uint2*)(lds + byte) = make_uint2(w0, w1);
        }
      __syncthreads();
      int tc = tid & 15, dbase = tid >> 4;
#pragma unroll
      for (int pass = 0; pass < 4; pass++) {
        int d = dbase + pass * 32;
        int byte = (d * 256 + tc * 16) ^ ((d & 7) << 4);
        uint4 v = *(const uint4*)(lds + byte);
        *(uint4*)(Vout + ((size_t)(bk * 128 + d)) * 2048 + t0g + tc * 8) = v;
      }
    }
  }
}

// ---------------- O-projection GEMM: 128x256 tile, 3-stage counted-vmcnt (r20-proven) ----------------
__global__ __launch_bounds__(512, 2) void k_gemm_o(
    const u16* __restrict__ A, const u16* __restrict__ BT, float* __restrict__ C) {
  __shared__ char lds[147456];  // 3 stages x (A 16K | B 32K)
  const int K = 2048;
  int tid = threadIdx.x, w = tid >> 6, l = tid & 63, lg = l >> 4, ll = l & 15;
  int wr = w >> 2, wc = w & 3;
  int lid = blockIdx.y * 8 + blockIdx.x;
  int xcd = lid & 7, r = lid >> 3;
  int colg = xcd & 1, rowg = xcd >> 1;
  int bxt = colg * 4 + (r & 3);
  int bm0 = (rowg * 8 + (r >> 2)) * 128;
  int bn0 = bxt * 256;

  auto stage = [&](int si, int kt) {
    char* Sb = lds + si * 49152;
    int k0 = kt * 64;
#pragma unroll
    for (int i = 0; i < 2; i++) {
      int base = i * 512 + (w << 6);
      int c = base + l;
      int row = c >> 3, kc = (c & 7) ^ (row & 7);
      gll16(A + (size_t)(bm0 + row) * K + k0 + kc * 8, Sb + base * 16);
    }
#pragma unroll
    for (int i = 0; i < 4; i++) {
      int base = i * 512 + (w << 6);
      int c = base + l;
      int row = c >> 3, kc = (c & 7) ^ (row & 7);
      gll16(BT + (size_t)(bn0 + row) * K + k0 + kc * 8, Sb + 16384 + base * 16);
    }
  };

  f32x4 acc[4][4] = {};
  stage(0, 0); stage(1, 1);
  asm volatile("s_waitcnt vmcnt(6)" ::: "memory");
  __builtin_amdgcn_s_barrier();
  __builtin_amdgcn_sched_barrier(0);

  for (int kt = 0; kt < 32; ++kt) {
    int cs = kt % 3;
    if (kt + 2 < 32) stage((kt + 2) % 3, kt + 2);
    char* As = lds + cs * 49152;
    char* Bs = As + 16384;
    __builtin_amdgcn_s_setprio(1);
#pragma unroll
    for (int ks = 0; ks < 2; ks++) {
      bf16x8 af[4], bf[4];
#pragma unroll
      for (int m = 0; m < 4; m++) {
        int row = 64 * wr + 16 * m + ll;
        af[m] = *(const bf16x8*)(As + row * 128 + (((lg + 4 * ks) ^ (row & 7)) << 4));
      }
#pragma unroll
      for (int n = 0; n < 4; n++) {
        int row = 64 * wc + 16 * n + ll;
        bf[n] = *(const bf16x8*)(Bs + row * 128 + (((lg + 4 * ks) ^ (row & 7)) << 4));
      }
#pragma unroll
      for (int m = 0; m < 4; m++)
#pragma unroll
        for (int n = 0; n < 4; n++)
          acc[m][n] = __builtin_amdgcn_mfma_f32_16x16x32_bf16(af[m], bf[n], acc[m][n], 0, 0, 0);
    }
    __builtin_amdgcn_s_setprio(0);
    if (kt + 2 < 32) {
      asm volatile("s_waitcnt vmcnt(6)" ::: "memory");
    } else {
      asm volatile("s_waitcnt vmcnt(0)" ::: "memory");
    }
    __builtin_amdgcn_s_barrier();
    __builtin_amdgcn_sched_barrier(0);
  }

#pragma unroll
  for (int m = 0; m < 4; m++)
#pragma unroll
    for (int n = 0; n < 4; n++) {
      int row = bm0 + 64 * wr + 16 * m + 4 * lg;
      int col = bn0 + 64 * wc + 16 * n + ll;
      float* cp = C + (size_t)row * 2048 + col;
#pragma unroll
      for (int r2 = 0; r2 < 4; r2++) cp[(size_t)r2 * 2048] = acc[m][n][r2];
    }
}

// ---------------- causal GQA flash attention: 4-heads-share-K/V (r19-proven) ----------------
__global__ __launch_bounds__(512, 2) void k_attn(
    const u16* __restrict__ Q, const u16* __restrict__ Kb,
    const u16* __restrict__ Vt, u16* __restrict__ Y) {
  __shared__ char lds[81920];  // K0 16K | V0 16K | K1 16K | V1 16K | P 16K
  char* Ps = lds + 65536;
  int tid = threadIdx.x, w = tid >> 6, l = tid & 63, lg = l >> 4, ll = l & 15;
  int fid = blockIdx.x;
  int g = fid & 7, rank = fid >> 3;   // rank 0..31
  int b = g >> 2, kvh = g & 3;
  int h = kvh * 4 + (w & 3);          // head per wave
  int rgrp = w >> 2;                  // row-group within the 32-row tile
  const u16* Kbase = Kb + ((size_t)b * 2048) * 512 + kvh * 128;
  const u16* Vbase = Vt + ((size_t)(b * 4 + kvh) * 128) * 2048;

  const bf16x8 vones = {(short)0x3F80, (short)0x3F80, (short)0x3F80, (short)0x3F80,
                        (short)0x3F80, (short)0x3F80, (short)0x3F80, (short)0x3F80};

  auto stage = [&](int bi, int k0) {
    char* Kd = lds + (bi ? 32768 : 0);
    char* Vd = Kd + 16384;
#pragma unroll
    for (int i = 0; i < 2; i++) {
      int base = i * 512 + (w << 6);
      int c = base + l;
      int dst = base * 16;
      int krow = c >> 4, ksrc = (c & 15) ^ (krow & 7);   // K tile [64][128]
      gll16(Kbase + (size_t)(k0 + krow) * 512 + ksrc * 8, Kd + dst);
      int vd = c >> 3, vsrc = (c & 7) ^ (vd & 7);        // V tile [128][64]
      gll16(Vbase + (size_t)vd * 2048 + k0 + vsrc * 8, Vd + dst);
    }
  };

#pragma unroll 1
  for (int qi = 0; qi < 2; qi++) {
    int qt = qi ? (63 - rank) : rank;   // 32-row q-tile index
    int q0 = qt * 32;
    int nt = (qt >> 1) + 1;             // KV tiles of 64 covering [0, q0+32)
    bf16x8 qf[4];
    {
      int qrow = b * 2048 + q0 + rgrp * 16 + ll;
      const u16* qp = Q + (size_t)qrow * 2048 + h * 128;
#pragma unroll
      for (int ks = 0; ks < 4; ks++) qf[ks] = *(const bf16x8*)(qp + ks * 32 + lg * 8);
    }
    f32x4 o[8] = {};
    f32x4 lacc = {};

    stage(0, 0);
    asm volatile("s_waitcnt vmcnt(0)" ::: "memory");
    __syncthreads();

    int cur = 0;
    for (int it = 0; it < nt; ++it) {
      if (it + 1 < nt) stage(cur ^ 1, (it + 1) * 64);
      char* Ks = lds + (cur ? 32768 : 0);
      char* Vs = Ks + 16384;
      f32x4 s[4] = {};
      __builtin_amdgcn_s_setprio(1);
#pragma unroll
      for (int ks = 0; ks < 4; ks++) {
#pragma unroll
        for (int n = 0; n < 4; n++) {
          int row = 16 * n + ll;
          bf16x8 kf = *(const bf16x8*)(Ks + ((row * 256 + (lg + 4 * ks) * 16) ^ ((row & 7) << 4)));
          s[n] = __builtin_amdgcn_mfma_f32_16x16x32_bf16(qf[ks], kf, s[n], 0, 0, 0);
        }
      }
      __builtin_amdgcn_s_setprio(0);
      if (it == nt - 1) {  // diagonal tile: causal mask
        int k0 = it * 64;
#pragma unroll
        for (int n = 0; n < 4; n++) {
          int kk = k0 + 16 * n + ll;
#pragma unroll
          for (int r = 0; r < 4; r++) {
            int qq = q0 + rgrp * 16 + 4 * lg + r;
            if (kk > qq) s[n][r] = -1e30f;
          }
        }
      }
      // STATIC-normalizer softmax: P = exp2(s) directly (r15-proven)
#pragma unroll
      for (int r = 0; r < 4; r++) {
        int prow = 4 * lg + r;
#pragma unroll
        for (int n = 0; n < 4; n++) {
          float e = exp2f(s[n][r]);
          int byte = (w << 11) + ((prow * 128 + (16 * n + ll) * 2) ^ ((prow & 7) << 4));
          *(u16*)(Ps + byte) = f2bf_fast(e);
        }
      }
      // O += P V ; l += P 1 (row-sum on the MFMA pipe)
      __builtin_amdgcn_s_setprio(1);
#pragma unroll
      for (int ks = 0; ks < 2; ks++) {
        bf16x8 pf = *(const bf16x8*)(Ps + (w << 11) + ((ll * 128 + (lg + 4 * ks) * 16) ^ ((ll & 7) << 4)));
        lacc = __builtin_amdgcn_mfma_f32_16x16x32_bf16(pf, vones, lacc, 0, 0, 0);
#pragma unroll
        for (int n = 0; n < 8; n++) {
          int row = 16 * n + ll;
          bf16x8 vf = *(const bf16x8*)(Vs + ((row * 128 + (lg + 4 * ks) * 16) ^ ((row & 7) << 4)));
          o[n] = __builtin_amdgcn_mfma_f32_16x16x32_bf16(pf, vf, o[n], 0, 0, 0);
        }
      }
      __builtin_amdgcn_s_setprio(0);
      asm volatile("s_waitcnt vmcnt(0)" ::: "memory");
      __syncthreads();
      cur ^= 1;
    }
    // output
    float rl[4];
#pragma unroll
    for (int r = 0; r < 4; r++) rl[r] = 1.0f / lacc[r];
#pragma unroll
    for (int n = 0; n < 8; n++) {
      int col = h * 128 + 16 * n + ll;
#pragma unroll
      for (int r = 0; r < 4; r++) {
        int trow = b * 2048 + q0 + rgrp * 16 + 4 * lg + r;
        Y[(size_t)trow * 2048 + col] = f2bf_fast(o[n][r] * rl[r]);
      }
    }
  }
}

extern "C" void kernel_launch(void* const* d_in, const int* in_sizes, int n_in,
                              void* d_out, int out_size, void* d_ws, size_t ws_size,
                              hipStream_t stream) {
  const float* x   = (const float*)d_in[0];
  const float* fc  = (const float*)d_in[1];
  const float* fs  = (const float*)d_in[2];
  const float* wq  = (const float*)d_in[3];
  const float* wk  = (const float*)d_in[4];
  const float* wv  = (const float*)d_in[5];
  const float* wo  = (const float*)d_in[6];
  const float* qnw = (const float*)d_in[7];
  const float* knw = (const float*)d_in[8];
  float* out = (float*)d_out;

  const size_t MB = 1ull << 20;
  char* ws = (char*)d_ws;
  u16*    xb   = (u16*)(ws);             // 16 MB  x bf16
  u16*    wqt  = (u16*)(ws + 16 * MB);   //  8 MB  wq^T bf16 [2048][2048]
  u16*    wkvt = (u16*)(ws + 24 * MB);   //  4 MB  [wk^T;wv^T] bf16 [1024][2048]
  u16*    wot  = (u16*)(ws + 28 * MB);   //  8 MB  wo^T bf16
  u16*    Qb   = (u16*)(ws + 36 * MB);   // 16 MB  Q' bf16 (rms+rope, x log2e/sqrt(D))
  u16*    Kbq  = (u16*)(ws + 52 * MB);   //  4 MB  K' bf16 (rms+rope)
  u16*    Vtg  = (u16*)(ws + 56 * MB);   //  4 MB  V^T bf16 (b,kvh,d,t)
  u16*    Yb   = (u16*)(ws + 60 * MB);   // 16 MB  attn out bf16
  float2* fcs  = (float2*)(ws + 76 * MB);//  1 MB  fused (cos,sin) table

  hipLaunchKernelGGL(k_prep, dim3(6720), dim3(256), 0, stream,
                     x, xb, wq, wqt, wk, wv, wkvt, wo, wot, fc, fs, fcs);
  hipLaunchKernelGGL(k_gemm_qkv, dim3(512), dim3(512), 0, stream,
                     xb, wqt, wkvt, Qb, Kbq, Vtg, qnw, knw, fcs);
  hipLaunchKernelGGL(k_attn, dim3(256), dim3(512), 0, stream, Qb, Kbq, Vtg, Yb);
  hipLaunchKernelGGL(k_gemm_o, dim3(8, 32), dim3(512), 0, stream, Yb, wot, out);
}